// Round 16
// baseline (259.700 us; speedup 1.0000x reference)
//
#include <hip/hip_runtime.h>

typedef _Float16 f16x8 __attribute__((ext_vector_type(8)));
typedef __fp16 fp16v2 __attribute__((ext_vector_type(2)));
typedef _Float16 f16v2 __attribute__((ext_vector_type(2)));
typedef short short8 __attribute__((ext_vector_type(8)));
typedef float f32x16 __attribute__((ext_vector_type(16)));

#define DD 512
#define NG 512

typedef __attribute__((address_space(3))) void lds_void;
typedef __attribute__((address_space(1))) void glb_void;

static __device__ __forceinline__ void gload_lds16(const void* g, void* l) {
  __builtin_amdgcn_global_load_lds((const glb_void*)g, (lds_void*)l, 16, 0, 0);
}

#define WAITV(n) asm volatile("s_waitcnt vmcnt(" #n ")" ::: "memory")
#define MEMFENCE asm volatile("" ::: "memory")

static __device__ __forceinline__ f16v2 pk16(float a, float b) {
  fp16v2 p = __builtin_amdgcn_cvt_pkrtz(a, b);
  return __builtin_bit_cast(f16v2, p);
}

// fast tanh: 1 - 2/(e^{2v}+1), native exp/rcp (~1e-6 abs err, saturates correctly)
static __device__ __forceinline__ float fast_tanh(float v) {
  float e = __expf(2.0f * v);
  return 1.0f - 2.0f * __builtin_amdgcn_rcpf(e + 1.0f);
}

// Whl layout (f16 RTE): [kt(32)][wstrip(8)][ct(2)][lane(64)=khalf*32+c31][8 f16]
// One (kt, wstrip) cell = 2 KB contiguous -> staged by that wave alone
// (wave-private ring).  B-fragment ds_read = ring + ct*1024 + lane*16:
// 1 KB contiguous per fragment -> zero bank conflicts (verified R4/R9/R11).
__global__ __launch_bounds__(256) void k_convert_w(const float* __restrict__ W,
                                                   unsigned char* __restrict__ Whl) {
  int t = blockIdx.x * 256 + threadIdx.x;   // 32768 = 512 W-rows x 64 kgroups(8)
  int r512 = t >> 6, kg = t & 63;           // r512 = output col
  int ws = r512 >> 6, c6 = r512 & 63;
  int ct = c6 >> 5, c31 = c6 & 31;
  int kt = kg >> 1, khalf = kg & 1;
  const float* p = W + (size_t)r512 * DD + kg * 8;
  short8 h;
#pragma unroll
  for (int j = 0; j < 8; ++j) {
    _Float16 hh = (_Float16)p[j];              // RTE
    h[j] = (short)__builtin_bit_cast(unsigned short, hh);
  }
  unsigned char* dst = Whl + (size_t)kt * 16384 + ws * 2048 + ct * 1024 +
                       (khalf * 32 + c31) * 16;
  *(short8*)dst = h;
}

// Fused GEMM(tanh-gate)+query-dot — barrier-free main loop.
// Block = 512 thr (8 waves) = 64 rows x 512 cols.  x-tile (64 rows) converted
// to f16 into 64 KB LDS in a prologue (slot^row XOR swizzle, conflict-free),
// ONE __syncthreads.  Each wave owns a private 64-col W strip streamed via a
// wave-private ring-3 (2 KB/kt, 2 gload_lds) -- no cross-wave LDS visibility
// -> NO barriers in the K-loop; per-wave vmcnt(4) self-pacing.
// Per wave-kt: 2 gloads + 4 ds_read_b128 + 4 MFMA (acc[2][2] = 64 AGPR).
// 114 KB LDS -> 1 block/CU; waves free-run like independent streams.
__global__ __launch_bounds__(512, 2) void k_gemm_score(
    const float* __restrict__ x, const unsigned char* __restrict__ Whl,
    const float* __restrict__ bias, const float* __restrict__ query,
    float* __restrict__ score, int N) {
  __shared__ unsigned char ldsX[65536];        // 64 rows x 64 slots(16B), slot^row
  __shared__ unsigned char ldsB[8][3][2048];   // per-wave private ring-3
  __shared__ float comb[8][64];
  const int tid = threadIdx.x;
  const int wave = tid >> 6;
  const int lane = tid & 63;
  const int l31 = lane & 31;
  const int kh = lane >> 5;
  const int brow0 = blockIdx.x * 64;

  // ---- x prologue: 64 rows f32 -> f16 LDS (8 rounds, coalesced 32B/lane) ----
#pragma unroll
  for (int i = 0; i < 8; ++i) {
    const int sg = i * 512 + tid;
    const int row = sg >> 6, sl = sg & 63;
    const float4* ps = (const float4*)(x + (size_t)(brow0 + row) * DD + sl * 8);
    const float4 u0 = ps[0];
    const float4 u1 = ps[1];
    f16v2 pa = pk16(u0.x, u0.y), pb = pk16(u0.z, u0.w);
    f16v2 pc = pk16(u1.x, u1.y), pd = pk16(u1.z, u1.w);
    f16x8 v = {pa[0], pa[1], pb[0], pb[1], pc[0], pc[1], pd[0], pd[1]};
    *(f16x8*)(&ldsX[row * 1024 + (sl ^ row) * 16]) = v;
  }

  // ---- B ring prologue: stage kt=0,1 (wave-private) ----
  const unsigned char* wsrc = Whl + (size_t)wave * 2048 + (size_t)lane * 16;
#define BSTAGE(KT)                                                          \
  do {                                                                      \
    const int km_ = (KT) & 31;                                              \
    const unsigned char* sb_ = wsrc + (size_t)km_ * 16384;                  \
    unsigned char* db_ = &ldsB[wave][(KT) % 3][0];                          \
    gload_lds16(sb_, db_);                                                  \
    gload_lds16(sb_ + 1024, db_ + 1024);                                    \
  } while (0)
  BSTAGE(0);
  MEMFENCE;
  BSTAGE(1);
  MEMFENCE;
  __syncthreads();   // the ONLY block-wide barrier before the epilogue

  f32x16 acc[2][2];
#pragma unroll
  for (int f = 0; f < 2; ++f)
#pragma unroll
    for (int c = 0; c < 2; ++c)
#pragma unroll
      for (int r = 0; r < 16; ++r) acc[f][c][r] = 0.f;

  const unsigned char* ax0 = &ldsX[l31 * 1024];          // f=0: row l31
  const unsigned char* ax1 = &ldsX[(32 + l31) * 1024];   // f=1: row 32+l31

  // ---- main loop: NO barriers; wave-private vmcnt pacing ----
#pragma unroll 4
  for (int kt = 0; kt < 32; ++kt) {
    BSTAGE(kt + 2);          // tail masked &31 (junk, never read)
    WAITV(4);                // slice kt landed (kt+1, kt+2 = 4 newer ops stay)
    MEMFENCE;
    const int s = kt * 2 + kh;
    f16x8 a0 = *(const f16x8*)(ax0 + ((s ^ l31) & 63) * 16);
    f16x8 a1 = *(const f16x8*)(ax1 + ((s ^ (32 + l31)) & 63) * 16);
    const unsigned char* bb = &ldsB[wave][kt % 3][lane * 16];
    f16x8 b0 = *(const f16x8*)(bb);
    f16x8 b1 = *(const f16x8*)(bb + 1024);
    __builtin_amdgcn_s_setprio(1);
    acc[0][0] = __builtin_amdgcn_mfma_f32_32x32x16_f16(a0, b0, acc[0][0], 0, 0, 0);
    acc[0][1] = __builtin_amdgcn_mfma_f32_32x32x16_f16(a0, b1, acc[0][1], 0, 0, 0);
    acc[1][0] = __builtin_amdgcn_mfma_f32_32x32x16_f16(a1, b0, acc[1][0], 0, 0, 0);
    acc[1][1] = __builtin_amdgcn_mfma_f32_32x32x16_f16(a1, b1, acc[1][1], 0, 0, 0);
    __builtin_amdgcn_s_setprio(0);
  }
  WAITV(0);   // drain junk tail stages before epilogue

  // ---- epilogue: tanh + query-dot over wave's 64 cols; combine 8 waves ----
  float sp[2][16];
#pragma unroll
  for (int f = 0; f < 2; ++f)
#pragma unroll
    for (int r = 0; r < 16; ++r) sp[f][r] = 0.f;
#pragma unroll
  for (int c = 0; c < 2; ++c) {
    const int col = wave * 64 + c * 32 + l31;
    const float bb2 = bias[col];
    const float qq = query[col];
#pragma unroll
    for (int f = 0; f < 2; ++f)
#pragma unroll
      for (int r = 0; r < 16; ++r)
        sp[f][r] += fast_tanh(acc[f][c][r] + bb2) * qq;
  }
#pragma unroll
  for (int f = 0; f < 2; ++f)
#pragma unroll
    for (int r = 0; r < 16; ++r) {
      float v = sp[f][r];
      v += __shfl_xor(v, 1);
      v += __shfl_xor(v, 2);
      v += __shfl_xor(v, 4);
      v += __shfl_xor(v, 8);
      v += __shfl_xor(v, 16);
      if (l31 == 0)  // C row = (r&3) + 8*(r>>2) + 4*kh  (m74/m101 layout)
        comb[wave][f * 32 + (r & 3) + 8 * (r >> 2) + 4 * kh] = v;
    }
  __syncthreads();
  if (tid < 64) {
    float sacc = 0.f;
#pragma unroll
    for (int w = 0; w < 8; ++w) sacc += comb[w][tid];
    score[brow0 + tid] = sacc;
  }
}

// Per-graph: segmented softmax over score + weighted sum of x rows -> out[g][512]
__global__ __launch_bounds__(256) void k_softmax_out(
    const float* __restrict__ x, const void* __restrict__ segp,
    const float* __restrict__ score, float* __restrict__ out, int N) {
  const int g = blockIdx.x;
  const int tid = threadIdx.x;

  // dtype probe: int64 element N/2-1 is a graph id (<NG) iff buffer is int64.
  const long long probe = ((const long long*)segp)[N / 2 - 1];
  const bool is64 = ((unsigned long long)probe < (unsigned long long)NG);
  const long long* s64 = (const long long*)segp;
  const int* s32 = (const int*)segp;

  int s0, s1;
  {
    int lo = 0, hi = N;
    while (lo < hi) {
      int m = (lo + hi) >> 1;
      long long v = is64 ? s64[m] : (long long)s32[m];
      if (v < (long long)g) lo = m + 1; else hi = m;
    }
    s0 = lo;
    lo = s0; hi = N;
    while (lo < hi) {
      int m = (lo + hi) >> 1;
      long long v = is64 ? s64[m] : (long long)s32[m];
      if (v < (long long)(g + 1)) lo = m + 1; else hi = m;
    }
    s1 = lo;
  }

  __shared__ float red[4];
  __shared__ float wbuf[512];

  float lm = -INFINITY;
  for (int i = s0 + tid; i < s1; i += 256) lm = fmaxf(lm, score[i]);
#pragma unroll
  for (int m = 1; m < 64; m <<= 1) lm = fmaxf(lm, __shfl_xor(lm, m));
  if ((tid & 63) == 0) red[tid >> 6] = lm;
  __syncthreads();
  const float mx = fmaxf(fmaxf(red[0], red[1]), fmaxf(red[2], red[3]));
  __syncthreads();

  float ls = 0.f;
  for (int i = s0 + tid; i < s1; i += 256) ls += expf(score[i] - mx);
#pragma unroll
  for (int m = 1; m < 64; m <<= 1) ls += __shfl_xor(ls, m);
  if ((tid & 63) == 0) red[tid >> 6] = ls;
  __syncthreads();
  const float sum = red[0] + red[1] + red[2] + red[3];
  const float inv = sum > 0.f ? 1.0f / sum : 0.f;

  float a0 = 0.f, a1 = 0.f;
  const int c = tid * 2;
  for (int base = s0; base < s1; base += 512) {
    const int cnt = min(512, s1 - base);
    __syncthreads();
    for (int i = tid; i < cnt; i += 256)
      wbuf[i] = expf(score[base + i] - mx) * inv;
    __syncthreads();
#pragma unroll 4
    for (int j = 0; j < cnt; ++j) {
      const float w = wbuf[j];
      const float2 xv = *(const float2*)(x + (size_t)(base + j) * DD + c);
      a0 = fmaf(w, xv.x, a0);
      a1 = fmaf(w, xv.y, a1);
    }
  }
  float* op = out + (size_t)g * DD + c;
  op[0] = a0;
  op[1] = a1;
}

extern "C" void kernel_launch(void* const* d_in, const int* in_sizes, int n_in,
                              void* d_out, int out_size, void* d_ws, size_t ws_size,
                              hipStream_t stream) {
  const float* x = (const float*)d_in[0];
  const void* seg = d_in[1];
  const float* W = (const float*)d_in[2];
  const float* b = (const float*)d_in[3];
  const float* q = (const float*)d_in[4];
  float* out = (float*)d_out;
  const int N = in_sizes[0] / DD;  // 131072

  unsigned char* Whl = (unsigned char*)d_ws;                 // 512 KB packed W (f16)
  float* score = (float*)(Whl + 524288);                     // N scores

  k_convert_w<<<128, 256, 0, stream>>>(W, Whl);
  k_gemm_score<<<N / 64, 512, 0, stream>>>(x, Whl, b, q, score, N);
  k_softmax_out<<<NG, 256, 0, stream>>>(x, seg, score, out, N);
}

// Round 17
// 180.223 us; speedup vs baseline: 1.4410x; 1.4410x over previous
//
#include <hip/hip_runtime.h>

typedef _Float16 f16x8 __attribute__((ext_vector_type(8)));
typedef _Float16 f16x4 __attribute__((ext_vector_type(4)));
typedef __fp16 fp16v2 __attribute__((ext_vector_type(2)));
typedef _Float16 f16v2 __attribute__((ext_vector_type(2)));
typedef short short8 __attribute__((ext_vector_type(8)));
typedef float f32x16 __attribute__((ext_vector_type(16)));

#define DD 512
#define NG 512

typedef __attribute__((address_space(3))) void lds_void;
typedef __attribute__((address_space(1))) void glb_void;

static __device__ __forceinline__ void gload_lds16(const void* g, void* l) {
  __builtin_amdgcn_global_load_lds((const glb_void*)g, (lds_void*)l, 16, 0, 0);
}

#define MEMFENCE asm volatile("" ::: "memory")

static __device__ __forceinline__ f16v2 pk16(float a, float b) {
  fp16v2 p = __builtin_amdgcn_cvt_pkrtz(a, b);
  return __builtin_bit_cast(f16v2, p);
}

// fast tanh: 1 - 2/(e^{2v}+1), native exp/rcp (~1e-6 abs err, saturates correctly)
static __device__ __forceinline__ float fast_tanh(float v) {
  float e = __expf(2.0f * v);
  return 1.0f - 2.0f * __builtin_amdgcn_rcpf(e + 1.0f);
}

// Whl layout (f16 RTE): [ny(2)][kt(32)][ct(8)][lane(64)=khalf*32+c31][8 f16]
// One (ny,kt) slice = 8 KB contiguous -> staged linearly by global_load_lds.
// B-fragment ds_read = lds + ct*1024 + lane*16: 64 lanes read 1024 contiguous
// bytes -> zero bank conflicts (verified rounds 4/9/11).
__global__ __launch_bounds__(256) void k_convert_w(const float* __restrict__ W,
                                                   unsigned char* __restrict__ Whl) {
  int t = blockIdx.x * 256 + threadIdx.x;   // 32768 = 512 W-rows x 64 kgroups(8)
  int r512 = t >> 6, kg = t & 63;
  int ny = r512 >> 8, col = r512 & 255;
  int ct = col >> 5, c31 = col & 31;
  int kt = kg >> 1, khalf = kg & 1;
  const float* p = W + (size_t)r512 * DD + kg * 8;
  short8 h;
#pragma unroll
  for (int j = 0; j < 8; ++j) {
    _Float16 hh = (_Float16)p[j];              // RTE
    h[j] = (short)__builtin_bit_cast(unsigned short, hh);
  }
  unsigned char* dst = Whl + (size_t)ny * 262144 + (size_t)kt * 8192 +
                       ct * 1024 + (khalf * 32 + c31) * 16;
  *(short8*)dst = h;
}

// Fused GEMM(tanh-gate)+query-dot.  R9 skeleton (best measured), fixed:
// Block = 256 thr / 4 waves (2 rg x 2 cg) = 64 rows x 256 cols (ny = half).
// Wave tile 32x128 (4 ct x 1 f16 MFMA, acc = 64 AGPR -> 4 blocks/CU).
// A: 1 float4/thread -> pkrtz -> 8B ds_write into 2 KB slice with
//    [kh-plane(1KB)][row(64)][16B] layout: writes 256B-contig/32-lane,
//    reads 512B-contig/32-lane -> ZERO bank conflicts both sides.
// B: global_load_lds ring-3 (8 KB slices, conflict-free verified).
// Body: vmcnt(3)+lgkm(0) -> barrier -> AWRITE(kt+2) -> AISSUE(kt+4) ->
//       BISSUE(kt+2) -> frags -> 4 MFMA (setprio).  30.7 KB LDS.
__global__ __launch_bounds__(256, 4) void k_gemm_score(
    const float* __restrict__ x, const unsigned char* __restrict__ Whl,
    const float* __restrict__ bias, const float* __restrict__ query,
    float* __restrict__ score_part, int N) {
  __shared__ unsigned char ldsB[3][8192];
  __shared__ unsigned char ldsA[3][2048];
  __shared__ float comb[2][64];
  const int tid = threadIdx.x;
  const int wave = tid >> 6;
  const int lane = tid & 63;
  const int l31 = lane & 31;
  const int kh = lane >> 5;          // k-half within fragment
  const int rg = wave >> 1;          // row-group (0,1): rows rg*32..rg*32+31
  const int cg = wave & 1;           // col-group (0,1): cts cg*4..cg*4+3
  const int ny = blockIdx.x;
  const int brow0 = blockIdx.y * 64;

  const unsigned char* wsrc = Whl + (size_t)ny * 262144 +
                              (size_t)wave * 2048 + (size_t)lane * 16;

  // A: thread t covers chunk (row = t>>2, kq = t&3) of the 64-row x 16-k slice.
  const float* asrc = x + (size_t)(brow0 + (tid >> 2)) * DD + (tid & 3) * 4;
  // write: [kh = kq>>1][row][ (kq&1)*8 ]  (1 KB per kh-plane)
  const int awoff = ((tid & 3) >> 1) * 1024 + (tid >> 2) * 16 + (tid & 1) * 8;
  // read: fragment of row rg*32 + l31, k-half kh
  const int aroff = kh * 1024 + (rg * 32 + l31) * 16;

  f32x16 acc[4];
#pragma unroll
  for (int j = 0; j < 4; ++j)
#pragma unroll
    for (int r = 0; r < 16; ++r) acc[j][r] = 0.f;

#define AISSUE(BUF, KT) do { BUF = *(const float4*)(asrc + ((KT) & 31) * 16); } while (0)

#define AWRITE(BUF, KT)                                                   \
  do {                                                                    \
    const int sl_ = (KT) % 3;                                             \
    f16v2 lo_ = pk16(BUF.x, BUF.y);                                       \
    f16v2 hi_ = pk16(BUF.z, BUF.w);                                       \
    f16x4 v_ = {lo_[0], lo_[1], hi_[0], hi_[1]};                          \
    *(f16x4*)(&ldsA[sl_][awoff]) = v_;                                    \
  } while (0)

#define BISSUE(KT)                                                        \
  do {                                                                    \
    const int sl_ = (KT) % 3;                                             \
    const unsigned char* sb_ = wsrc + (size_t)((KT) & 31) * 8192;         \
    gload_lds16(sb_, &ldsB[sl_][wave * 2048]);                            \
    gload_lds16(sb_ + 1024, &ldsB[sl_][wave * 2048 + 1024]);              \
  } while (0)

  float4 aP, aQ;
  // prologue: A(0),A(1) staged (one-time full drain); pipe filled in FIFO
  // order [A(2), B(0)x2, A(3), B(1)x2] = 6 outstanding entering body 0.
  AISSUE(aP, 0);
  MEMFENCE;
  AISSUE(aQ, 1);
  MEMFENCE;
  asm volatile("s_waitcnt vmcnt(0)" ::: "memory");
  AWRITE(aP, 0);
  AWRITE(aQ, 1);
  MEMFENCE;
  AISSUE(aP, 2);
  MEMFENCE;
  BISSUE(0);
  MEMFENCE;
  AISSUE(aQ, 3);
  MEMFENCE;
  BISSUE(1);
  MEMFENCE;

  // body kt: vmcnt(3) drains [A(kt+2), B(kt)] (3 newer: A(kt+3), B(kt+1)x2);
  // lgkm(0)+barrier make all waves' A-writes/frag-reads of kt-1 visible/done.
#define BODY(KT, CUR)                                                     \
  do {                                                                    \
    asm volatile("s_waitcnt vmcnt(3) lgkmcnt(0)" ::: "memory");           \
    __builtin_amdgcn_s_barrier();                                         \
    MEMFENCE;                                                             \
    AWRITE(CUR, (KT) + 2);                                                \
    MEMFENCE;                                                             \
    AISSUE(CUR, (KT) + 4);                                                \
    MEMFENCE;                                                             \
    BISSUE((KT) + 2);                                                     \
    MEMFENCE;                                                             \
    const int slot_ = (KT) % 3;                                           \
    f16x8 a_ = *(const f16x8*)(&ldsA[slot_][aroff]);                      \
    const unsigned char* bb_ = &ldsB[slot_][lane * 16 + cg * 4096];       \
    __builtin_amdgcn_s_setprio(1);                                        \
    _Pragma("unroll")                                                     \
    for (int j = 0; j < 4; ++j) {                                         \
      f16x8 bh_ = *(const f16x8*)(bb_ + j * 1024);                        \
      acc[j] = __builtin_amdgcn_mfma_f32_32x32x16_f16(a_, bh_, acc[j], 0, 0, 0); \
    }                                                                     \
    __builtin_amdgcn_s_setprio(0);                                        \
  } while (0)

#pragma unroll 1
  for (int it = 0; it < 16; ++it) {
    BODY(it * 2, aP);
    BODY(it * 2 + 1, aQ);
  }

  // epilogue: tanh + query-dot; 32-lane reduce; combine cg halves via comb
  float sp[16];
#pragma unroll
  for (int r = 0; r < 16; ++r) sp[r] = 0.f;
#pragma unroll
  for (int j = 0; j < 4; ++j) {
    const int col = ny * 256 + (cg * 4 + j) * 32 + l31;
    const float bb2 = bias[col];
    const float qq = query[col];
#pragma unroll
    for (int r = 0; r < 16; ++r)
      sp[r] += fast_tanh(acc[j][r] + bb2) * qq;
  }
  __syncthreads();
#pragma unroll
  for (int r = 0; r < 16; ++r) {
    float v = sp[r];
    v += __shfl_xor(v, 1);
    v += __shfl_xor(v, 2);
    v += __shfl_xor(v, 4);
    v += __shfl_xor(v, 8);
    v += __shfl_xor(v, 16);
    if (l31 == 0)  // C row = (r&3) + 8*(r>>2) + 4*kh  (m74/m101 layout)
      comb[cg][rg * 32 + (r & 3) + 8 * (r >> 2) + 4 * kh] = v;
  }
  __syncthreads();
  if (tid < 64)
    score_part[(size_t)ny * N + brow0 + tid] = comb[0][tid] + comb[1][tid];
}

// Per-graph: segmented softmax over (sp0+sp1) + weighted sum of x rows -> out[g][512]
__global__ __launch_bounds__(256) void k_softmax_out(
    const float* __restrict__ x, const void* __restrict__ segp,
    const float* __restrict__ sp0, const float* __restrict__ sp1,
    float* __restrict__ out, int N) {
  const int g = blockIdx.x;
  const int tid = threadIdx.x;

  // dtype probe: int64 element N/2-1 is a graph id (<NG) iff buffer is int64.
  const long long probe = ((const long long*)segp)[N / 2 - 1];
  const bool is64 = ((unsigned long long)probe < (unsigned long long)NG);
  const long long* s64 = (const long long*)segp;
  const int* s32 = (const int*)segp;

  int s0, s1;
  {
    int lo = 0, hi = N;
    while (lo < hi) {
      int m = (lo + hi) >> 1;
      long long v = is64 ? s64[m] : (long long)s32[m];
      if (v < (long long)g) lo = m + 1; else hi = m;
    }
    s0 = lo;
    lo = s0; hi = N;
    while (lo < hi) {
      int m = (lo + hi) >> 1;
      long long v = is64 ? s64[m] : (long long)s32[m];
      if (v < (long long)(g + 1)) lo = m + 1; else hi = m;
    }
    s1 = lo;
  }

  __shared__ float red[4];
  __shared__ float wbuf[512];

  float lm = -INFINITY;
  for (int i = s0 + tid; i < s1; i += 256) lm = fmaxf(lm, sp0[i] + sp1[i]);
#pragma unroll
  for (int m = 1; m < 64; m <<= 1) lm = fmaxf(lm, __shfl_xor(lm, m));
  if ((tid & 63) == 0) red[tid >> 6] = lm;
  __syncthreads();
  const float mx = fmaxf(fmaxf(red[0], red[1]), fmaxf(red[2], red[3]));
  __syncthreads();

  float ls = 0.f;
  for (int i = s0 + tid; i < s1; i += 256) ls += expf(sp0[i] + sp1[i] - mx);
#pragma unroll
  for (int m = 1; m < 64; m <<= 1) ls += __shfl_xor(ls, m);
  if ((tid & 63) == 0) red[tid >> 6] = ls;
  __syncthreads();
  const float sum = red[0] + red[1] + red[2] + red[3];
  const float inv = sum > 0.f ? 1.0f / sum : 0.f;

  float a0 = 0.f, a1 = 0.f;
  const int c = tid * 2;
  for (int base = s0; base < s1; base += 512) {
    const int cnt = min(512, s1 - base);
    __syncthreads();
    for (int i = tid; i < cnt; i += 256)
      wbuf[i] = expf(sp0[base + i] + sp1[base + i] - mx) * inv;
    __syncthreads();
#pragma unroll 4
    for (int j = 0; j < cnt; ++j) {
      const float w = wbuf[j];
      const float2 xv = *(const float2*)(x + (size_t)(base + j) * DD + c);
      a0 = fmaf(w, xv.x, a0);
      a1 = fmaf(w, xv.y, a1);
    }
  }
  float* op = out + (size_t)g * DD + c;
  op[0] = a0;
  op[1] = a1;
}

extern "C" void kernel_launch(void* const* d_in, const int* in_sizes, int n_in,
                              void* d_out, int out_size, void* d_ws, size_t ws_size,
                              hipStream_t stream) {
  const float* x = (const float*)d_in[0];
  const void* seg = d_in[1];
  const float* W = (const float*)d_in[2];
  const float* b = (const float*)d_in[3];
  const float* q = (const float*)d_in[4];
  float* out = (float*)d_out;
  const int N = in_sizes[0] / DD;  // 131072

  unsigned char* Whl = (unsigned char*)d_ws;                 // 512 KB packed W (f16)
  float* sp0 = (float*)(Whl + 524288);                       // N partial scores (ny=0)
  float* sp1 = sp0 + N;                                      // N partial scores (ny=1)

  k_convert_w<<<128, 256, 0, stream>>>(W, Whl);
  dim3 grid(2, N / 64);                                      // ny fastest -> x-row cache reuse
  k_gemm_score<<<grid, 256, 0, stream>>>(x, Whl, b, q, sp0, N);
  k_softmax_out<<<NG, 256, 0, stream>>>(x, seg, sp0, sp1, out, N);
}

// Round 18
// 176.535 us; speedup vs baseline: 1.4711x; 1.0209x over previous
//
#include <hip/hip_runtime.h>

typedef _Float16 f16x8 __attribute__((ext_vector_type(8)));
typedef _Float16 f16x4 __attribute__((ext_vector_type(4)));
typedef __fp16 fp16v2 __attribute__((ext_vector_type(2)));
typedef _Float16 f16v2 __attribute__((ext_vector_type(2)));
typedef short short8 __attribute__((ext_vector_type(8)));
typedef float f32x16 __attribute__((ext_vector_type(16)));

#define DD 512
#define NG 512

typedef __attribute__((address_space(3))) void lds_void;
typedef __attribute__((address_space(1))) void glb_void;

static __device__ __forceinline__ void gload_lds16(const void* g, void* l) {
  __builtin_amdgcn_global_load_lds((const glb_void*)g, (lds_void*)l, 16, 0, 0);
}

#define MEMFENCE asm volatile("" ::: "memory")

static __device__ __forceinline__ f16v2 pk16(float a, float b) {
  fp16v2 p = __builtin_amdgcn_cvt_pkrtz(a, b);
  return __builtin_bit_cast(f16v2, p);
}

// fast tanh: 1 - 2/(e^{2v}+1), native exp/rcp (~1e-6 abs err, saturates correctly)
static __device__ __forceinline__ float fast_tanh(float v) {
  float e = __expf(2.0f * v);
  return 1.0f - 2.0f * __builtin_amdgcn_rcpf(e + 1.0f);
}

// Whl layout (f16 RTE): [ny(2)][kt(32)][ct(8)][lane(64)=khalf*32+c31][8 f16]
// One (ny,kt) slice = 8 KB contiguous -> staged linearly by global_load_lds.
// B-fragment ds_read = lds + ct*1024 + lane*16: 64 lanes read 1024 contiguous
// bytes -> zero bank conflicts (verified rounds 4/9/11/17).
__global__ __launch_bounds__(256) void k_convert_w(const float* __restrict__ W,
                                                   unsigned char* __restrict__ Whl) {
  int t = blockIdx.x * 256 + threadIdx.x;   // 32768 = 512 W-rows x 64 kgroups(8)
  int r512 = t >> 6, kg = t & 63;
  int ny = r512 >> 8, col = r512 & 255;
  int ct = col >> 5, c31 = col & 31;
  int kt = kg >> 1, khalf = kg & 1;
  const float* p = W + (size_t)r512 * DD + kg * 8;
  short8 h;
#pragma unroll
  for (int j = 0; j < 8; ++j) {
    _Float16 hh = (_Float16)p[j];              // RTE
    h[j] = (short)__builtin_bit_cast(unsigned short, hh);
  }
  unsigned char* dst = Whl + (size_t)ny * 262144 + (size_t)kt * 8192 +
                       ct * 1024 + (khalf * 32 + c31) * 16;
  *(short8*)dst = h;
}

// Fused GEMM(tanh-gate)+query-dot.  Best-measured geometry (R9/R13): wave =
// 64 rows x 128 cols (2 row-frags x 4 ct, acc[2][4] = 128 AGPR); block =
// 4 waves (2 rg x 2 cg) = 128 rows x 256 cols (ny = col half).
// NEW: 2-kt bodies (16 barriers, not 32) + f16 A in conflict-free
// [kh-plane][row][16B] layout + ring-2 double-buffer (B 16KB + A 8KB /buf).
// Body S: drain -> barrier -> AWRITE(S+1) -> AISSUE(S+2) -> BISSUE(S+1) ->
// compute slice S (16 MFMA/wave).  49 KB LDS.
__global__ __launch_bounds__(256, 2) void k_gemm_score(
    const float* __restrict__ x, const unsigned char* __restrict__ Whl,
    const float* __restrict__ bias, const float* __restrict__ query,
    float* __restrict__ score_part, int N) {
  __shared__ unsigned char ldsB[2][16384];
  __shared__ unsigned char ldsA[2][8192];
  __shared__ float comb[2][128];
  const int tid = threadIdx.x;
  const int wave = tid >> 6;
  const int lane = tid & 63;
  const int l31 = lane & 31;
  const int kh = lane >> 5;          // k-half within fragment
  const int rg = wave >> 1;          // row-group: rows rg*64..rg*64+63
  const int cg = wave & 1;           // col-group: cts cg*4..cg*4+3
  const int ny = blockIdx.x;
  const int brow0 = blockIdx.y * 128;

  const unsigned char* wsrc = Whl + (size_t)ny * 262144 +
                              (size_t)wave * 2048 + (size_t)lane * 16;

  // A: thread covers chunks (row = tid>>2 and +64, kq = tid&3) of each
  // 128-row x 16-k slice.  asrc strides: +c*64*DD rows, +kt*16 k-window.
  const float* asrc = x + (size_t)(brow0 + (tid >> 2)) * DD + (tid & 3) * 4;
  // f16 write: [kt-in-pair(4KB)][kh(2KB)][row(128)x16B], half = kq&1:
  const int awoff = ((tid & 3) >> 1) * 2048 + (tid >> 2) * 16 + (tid & 1) * 8;
  // f16 read: fragment row rg*64 + f*32 + l31, plane kh
  const int aroff = kh * 2048 + (rg * 64 + l31) * 16;

  f32x16 acc[2][4];
#pragma unroll
  for (int f = 0; f < 2; ++f)
#pragma unroll
    for (int j = 0; j < 4; ++j)
#pragma unroll
      for (int r = 0; r < 16; ++r) acc[f][j][r] = 0.f;

  float4 aB[4];   // [kt-in-pair][chunk c]

#define AISSUE(S)                                                           \
  do {                                                                      \
    _Pragma("unroll")                                                       \
    for (int j = 0; j < 2; ++j)                                             \
      _Pragma("unroll")                                                     \
      for (int c = 0; c < 2; ++c)                                           \
        aB[j * 2 + c] = *(const float4*)(asrc + (size_t)c * 64 * DD +       \
                                         ((2 * (S) + j) & 31) * 16);        \
  } while (0)

#define AWRITE(S)                                                           \
  do {                                                                      \
    unsigned char* base_ = &ldsA[(S) & 1][0];                               \
    _Pragma("unroll")                                                       \
    for (int j = 0; j < 2; ++j)                                             \
      _Pragma("unroll")                                                     \
      for (int c = 0; c < 2; ++c) {                                         \
        const float4 v_ = aB[j * 2 + c];                                    \
        f16v2 lo_ = pk16(v_.x, v_.y);                                       \
        f16v2 hi_ = pk16(v_.z, v_.w);                                       \
        f16x4 w_ = {lo_[0], lo_[1], hi_[0], hi_[1]};                        \
        *(f16x4*)(base_ + j * 4096 + awoff + c * 1024) = w_;                \
      }                                                                     \
  } while (0)

#define BISSUE(S)                                                           \
  do {                                                                      \
    unsigned char* db_ = &ldsB[(S) & 1][wave * 2048];                       \
    _Pragma("unroll")                                                       \
    for (int j = 0; j < 2; ++j) {                                           \
      const unsigned char* sb_ = wsrc + (size_t)((2 * (S) + j) & 31) * 8192;\
      gload_lds16(sb_, db_ + j * 8192);                                     \
      gload_lds16(sb_ + 1024, db_ + j * 8192 + 1024);                       \
    }                                                                       \
  } while (0)

  // prologue: regs<-A(0); drain; LDS<-A(0); regs<-A(1); B(0) staged.
  AISSUE(0);
  MEMFENCE;
  asm volatile("s_waitcnt vmcnt(0)" ::: "memory");
  AWRITE(0);
  AISSUE(1);
  MEMFENCE;
  BISSUE(0);
  MEMFENCE;

#define BODY(S)                                                             \
  do {                                                                      \
    asm volatile("s_waitcnt vmcnt(0) lgkmcnt(0)" ::: "memory");             \
    __builtin_amdgcn_s_barrier();                                           \
    MEMFENCE;                                                               \
    AWRITE((S) + 1);      /* slot (S+1)&1; its readers done (barrier) */    \
    MEMFENCE;                                                               \
    AISSUE(((S) + 2) & 15);                                                 \
    MEMFENCE;                                                               \
    BISSUE((S) + 1);      /* junk at S=15 (kts 0,1) - never read */         \
    MEMFENCE;                                                               \
    const unsigned char* ap_ = &ldsA[(S) & 1][0];                           \
    const unsigned char* bp_ = &ldsB[(S) & 1][cg * 4096 + lane * 16];       \
    __builtin_amdgcn_s_setprio(1);                                          \
    _Pragma("unroll")                                                       \
    for (int j = 0; j < 2; ++j) {                                           \
      f16x8 a0_ = *(const f16x8*)(ap_ + j * 4096 + aroff);                  \
      f16x8 a1_ = *(const f16x8*)(ap_ + j * 4096 + aroff + 512);            \
      const unsigned char* bb_ = bp_ + j * 8192;                            \
      _Pragma("unroll")                                                     \
      for (int t = 0; t < 4; ++t) {                                         \
        f16x8 bh_ = *(const f16x8*)(bb_ + t * 1024);                        \
        acc[0][t] = __builtin_amdgcn_mfma_f32_32x32x16_f16(a0_, bh_, acc[0][t], 0, 0, 0); \
        acc[1][t] = __builtin_amdgcn_mfma_f32_32x32x16_f16(a1_, bh_, acc[1][t], 0, 0, 0); \
      }                                                                     \
    }                                                                       \
    __builtin_amdgcn_s_setprio(0);                                          \
  } while (0)

#pragma unroll 1
  for (int it = 0; it < 8; ++it) {
    BODY(it * 2);
    BODY(it * 2 + 1);
  }

  // epilogue: tanh + query-dot; 32-lane reduce; combine cg halves
  float sp[2][16];
#pragma unroll
  for (int f = 0; f < 2; ++f)
#pragma unroll
    for (int r = 0; r < 16; ++r) sp[f][r] = 0.f;
#pragma unroll
  for (int j = 0; j < 4; ++j) {
    const int col = ny * 256 + (cg * 4 + j) * 32 + l31;
    const float bb2 = bias[col];
    const float qq = query[col];
#pragma unroll
    for (int f = 0; f < 2; ++f)
#pragma unroll
      for (int r = 0; r < 16; ++r)
        sp[f][r] += fast_tanh(acc[f][j][r] + bb2) * qq;
  }
  __syncthreads();
#pragma unroll
  for (int f = 0; f < 2; ++f)
#pragma unroll
    for (int r = 0; r < 16; ++r) {
      float v = sp[f][r];
      v += __shfl_xor(v, 1);
      v += __shfl_xor(v, 2);
      v += __shfl_xor(v, 4);
      v += __shfl_xor(v, 8);
      v += __shfl_xor(v, 16);
      if (l31 == 0)  // C row = (r&3) + 8*(r>>2) + 4*kh  (m74/m101 layout)
        comb[cg][rg * 64 + f * 32 + (r & 3) + 8 * (r >> 2) + 4 * kh] = v;
    }
  __syncthreads();
  if (tid < 128)
    score_part[(size_t)ny * N + brow0 + tid] = comb[0][tid] + comb[1][tid];
}

// Per-graph: segmented softmax over (sp0+sp1) + weighted sum of x rows -> out[g][512]
__global__ __launch_bounds__(256) void k_softmax_out(
    const float* __restrict__ x, const void* __restrict__ segp,
    const float* __restrict__ sp0, const float* __restrict__ sp1,
    float* __restrict__ out, int N) {
  const int g = blockIdx.x;
  const int tid = threadIdx.x;

  // dtype probe: int64 element N/2-1 is a graph id (<NG) iff buffer is int64.
  const long long probe = ((const long long*)segp)[N / 2 - 1];
  const bool is64 = ((unsigned long long)probe < (unsigned long long)NG);
  const long long* s64 = (const long long*)segp;
  const int* s32 = (const int*)segp;

  int s0, s1;
  {
    int lo = 0, hi = N;
    while (lo < hi) {
      int m = (lo + hi) >> 1;
      long long v = is64 ? s64[m] : (long long)s32[m];
      if (v < (long long)g) lo = m + 1; else hi = m;
    }
    s0 = lo;
    lo = s0; hi = N;
    while (lo < hi) {
      int m = (lo + hi) >> 1;
      long long v = is64 ? s64[m] : (long long)s32[m];
      if (v < (long long)(g + 1)) lo = m + 1; else hi = m;
    }
    s1 = lo;
  }

  __shared__ float red[4];
  __shared__ float wbuf[512];

  float lm = -INFINITY;
  for (int i = s0 + tid; i < s1; i += 256) lm = fmaxf(lm, sp0[i] + sp1[i]);
#pragma unroll
  for (int m = 1; m < 64; m <<= 1) lm = fmaxf(lm, __shfl_xor(lm, m));
  if ((tid & 63) == 0) red[tid >> 6] = lm;
  __syncthreads();
  const float mx = fmaxf(fmaxf(red[0], red[1]), fmaxf(red[2], red[3]));
  __syncthreads();

  float ls = 0.f;
  for (int i = s0 + tid; i < s1; i += 256) ls += expf(sp0[i] + sp1[i] - mx);
#pragma unroll
  for (int m = 1; m < 64; m <<= 1) ls += __shfl_xor(ls, m);
  if ((tid & 63) == 0) red[tid >> 6] = ls;
  __syncthreads();
  const float sum = red[0] + red[1] + red[2] + red[3];
  const float inv = sum > 0.f ? 1.0f / sum : 0.f;

  float a0 = 0.f, a1 = 0.f;
  const int c = tid * 2;
  for (int base = s0; base < s1; base += 512) {
    const int cnt = min(512, s1 - base);
    __syncthreads();
    for (int i = tid; i < cnt; i += 256)
      wbuf[i] = expf(sp0[base + i] + sp1[base + i] - mx) * inv;
    __syncthreads();
#pragma unroll 4
    for (int j = 0; j < cnt; ++j) {
      const float w = wbuf[j];
      const float2 xv = *(const float2*)(x + (size_t)(base + j) * DD + c);
      a0 = fmaf(w, xv.x, a0);
      a1 = fmaf(w, xv.y, a1);
    }
  }
  float* op = out + (size_t)g * DD + c;
  op[0] = a0;
  op[1] = a1;
}

extern "C" void kernel_launch(void* const* d_in, const int* in_sizes, int n_in,
                              void* d_out, int out_size, void* d_ws, size_t ws_size,
                              hipStream_t stream) {
  const float* x = (const float*)d_in[0];
  const void* seg = d_in[1];
  const float* W = (const float*)d_in[2];
  const float* b = (const float*)d_in[3];
  const float* q = (const float*)d_in[4];
  float* out = (float*)d_out;
  const int N = in_sizes[0] / DD;  // 131072

  unsigned char* Whl = (unsigned char*)d_ws;                 // 512 KB packed W (f16)
  float* sp0 = (float*)(Whl + 524288);                       // N partial scores (ny=0)
  float* sp1 = sp0 + N;                                      // N partial scores (ny=1)

  k_convert_w<<<128, 256, 0, stream>>>(W, Whl);
  dim3 grid(2, N / 128);                                     // ny fastest -> x-row cache reuse
  k_gemm_score<<<grid, 256, 0, stream>>>(x, Whl, b, q, sp0, N);
  k_softmax_out<<<NG, 256, 0, stream>>>(x, seg, sp0, sp1, out, N);
}

// Round 19
// 174.967 us; speedup vs baseline: 1.4843x; 1.0090x over previous
//
#include <hip/hip_runtime.h>

typedef _Float16 f16x8 __attribute__((ext_vector_type(8)));
typedef _Float16 f16x4 __attribute__((ext_vector_type(4)));
typedef __fp16 fp16v2 __attribute__((ext_vector_type(2)));
typedef _Float16 f16v2 __attribute__((ext_vector_type(2)));
typedef short short8 __attribute__((ext_vector_type(8)));
typedef float f32x16 __attribute__((ext_vector_type(16)));

#define DD 512
#define NG 512

typedef __attribute__((address_space(3))) void lds_void;
typedef __attribute__((address_space(1))) void glb_void;

static __device__ __forceinline__ void gload_lds16(const void* g, void* l) {
  __builtin_amdgcn_global_load_lds((const glb_void*)g, (lds_void*)l, 16, 0, 0);
}

#define MEMFENCE asm volatile("" ::: "memory")

static __device__ __forceinline__ f16v2 pk16(float a, float b) {
  fp16v2 p = __builtin_amdgcn_cvt_pkrtz(a, b);
  return __builtin_bit_cast(f16v2, p);
}

// fast tanh: 1 - 2/(e^{2v}+1), native exp/rcp (~1e-6 abs err, saturates correctly)
static __device__ __forceinline__ float fast_tanh(float v) {
  float e = __expf(2.0f * v);
  return 1.0f - 2.0f * __builtin_amdgcn_rcpf(e + 1.0f);
}

// Whl layout (f16 RTE): [ny(2)][kt(32)][ct(8)][lane(64)=khalf*32+c31][8 f16]
// One (ny,kt) slice = 8 KB contiguous -> staged linearly by global_load_lds.
// B-fragment ds_read = lds + ct*1024 + lane*16: 64 lanes read 1024 contiguous
// bytes -> zero bank conflicts (verified rounds 4/9/11/17).
__global__ __launch_bounds__(256) void k_convert_w(const float* __restrict__ W,
                                                   unsigned char* __restrict__ Whl) {
  int t = blockIdx.x * 256 + threadIdx.x;   // 32768 = 512 W-rows x 64 kgroups(8)
  int r512 = t >> 6, kg = t & 63;
  int ny = r512 >> 8, col = r512 & 255;
  int ct = col >> 5, c31 = col & 31;
  int kt = kg >> 1, khalf = kg & 1;
  const float* p = W + (size_t)r512 * DD + kg * 8;
  short8 h;
#pragma unroll
  for (int j = 0; j < 8; ++j) {
    _Float16 hh = (_Float16)p[j];              // RTE
    h[j] = (short)__builtin_bit_cast(unsigned short, hh);
  }
  unsigned char* dst = Whl + (size_t)ny * 262144 + (size_t)kt * 8192 +
                       ct * 1024 + (khalf * 32 + c31) * 16;
  *(short8*)dst = h;
}

// Fused GEMM(tanh-gate)+query-dot.  R18 dataflow (best measured: 157 us),
// rescheduled: counted vmcnt(4) drains + AWRITE/AISSUE moved AFTER the MFMA
// cluster so MFMA waits only on B-landing.  FIFO invariant at body top:
// [B(S) x4 older, A(S+1) x4 newer] -> vmcnt(4) exact.
// Wave = 64 rows x 128 cols (acc[2][4] = 128 AGPR); block = 4 waves = 128
// rows x 256 cols (ny = col half); 2-kt bodies (16 barriers); ring-2
// double-buffer (B 16KB + A 8KB per buf); f16 A in conflict-free
// [kh-plane][row][16B] layout.  49 KB LDS -> 2 blocks/CU.
__global__ __launch_bounds__(256, 2) void k_gemm_score(
    const float* __restrict__ x, const unsigned char* __restrict__ Whl,
    const float* __restrict__ bias, const float* __restrict__ query,
    float* __restrict__ score_part, int N) {
  __shared__ unsigned char ldsB[2][16384];
  __shared__ unsigned char ldsA[2][8192];
  __shared__ float comb[2][128];
  const int tid = threadIdx.x;
  const int wave = tid >> 6;
  const int lane = tid & 63;
  const int l31 = lane & 31;
  const int kh = lane >> 5;          // k-half within fragment
  const int rg = wave >> 1;          // row-group: rows rg*64..rg*64+63
  const int cg = wave & 1;           // col-group: cts cg*4..cg*4+3
  const int ny = blockIdx.x;
  const int brow0 = blockIdx.y * 128;

  const unsigned char* wsrc = Whl + (size_t)ny * 262144 +
                              (size_t)wave * 2048 + (size_t)lane * 16;

  // A: thread covers chunks (row = tid>>2 and +64, kq = tid&3) of each
  // 128-row x 16-k slice.
  const float* asrc = x + (size_t)(brow0 + (tid >> 2)) * DD + (tid & 3) * 4;
  // f16 write: [kt-in-pair(4KB)][kh(2KB)][row(128)x16B], half = kq&1:
  const int awoff = ((tid & 3) >> 1) * 2048 + (tid >> 2) * 16 + (tid & 1) * 8;
  // f16 read: fragment row rg*64 + f*32 + l31, plane kh
  const int aroff = kh * 2048 + (rg * 64 + l31) * 16;

  f32x16 acc[2][4];
#pragma unroll
  for (int f = 0; f < 2; ++f)
#pragma unroll
    for (int j = 0; j < 4; ++j)
#pragma unroll
      for (int r = 0; r < 16; ++r) acc[f][j][r] = 0.f;

  float4 aB[4];   // [kt-in-pair][chunk c]

#define AISSUE(S)                                                           \
  do {                                                                      \
    _Pragma("unroll")                                                       \
    for (int j = 0; j < 2; ++j)                                             \
      _Pragma("unroll")                                                     \
      for (int c = 0; c < 2; ++c)                                           \
        aB[j * 2 + c] = *(const float4*)(asrc + (size_t)c * 64 * DD +       \
                                         ((2 * (S) + j) & 31) * 16);        \
  } while (0)

#define AWRITE(S)                                                           \
  do {                                                                      \
    unsigned char* base_ = &ldsA[(S) & 1][0];                               \
    _Pragma("unroll")                                                       \
    for (int j = 0; j < 2; ++j)                                             \
      _Pragma("unroll")                                                     \
      for (int c = 0; c < 2; ++c) {                                         \
        const float4 v_ = aB[j * 2 + c];                                    \
        f16v2 lo_ = pk16(v_.x, v_.y);                                       \
        f16v2 hi_ = pk16(v_.z, v_.w);                                       \
        f16x4 w_ = {lo_[0], lo_[1], hi_[0], hi_[1]};                        \
        *(f16x4*)(base_ + j * 4096 + awoff + c * 1024) = w_;                \
      }                                                                     \
  } while (0)

#define BISSUE(S)                                                           \
  do {                                                                      \
    unsigned char* db_ = &ldsB[(S) & 1][wave * 2048];                       \
    _Pragma("unroll")                                                       \
    for (int j = 0; j < 2; ++j) {                                           \
      const unsigned char* sb_ = wsrc + (size_t)((2 * (S) + j) & 31) * 8192;\
      gload_lds16(sb_, db_ + j * 8192);                                     \
      gload_lds16(sb_ + 1024, db_ + j * 8192 + 1024);                       \
    }                                                                       \
  } while (0)

  // prologue: regs<-A(0); drain; LDS<-A(0); B(0) staged (OLDER); regs<-A(1)
  // (NEWER) -> body-0 top sees FIFO [B(0)x4, A(1)x4].
  AISSUE(0);
  MEMFENCE;
  asm volatile("s_waitcnt vmcnt(0)" ::: "memory");
  AWRITE(0);
  MEMFENCE;
  BISSUE(0);
  MEMFENCE;
  AISSUE(1);
  MEMFENCE;

  // BODY(S): vmcnt(4) drains B(S) only; lgkm(0) drains prior A ds_writes;
  // barrier; BISSUE(S+1); MFMA on slice S; vmcnt(4) drains A(S+1) regs
  // (leaves B(S+1) in flight); AWRITE(S+1); AISSUE(S+2).
#define BODY(S)                                                             \
  do {                                                                      \
    asm volatile("s_waitcnt vmcnt(4) lgkmcnt(0)" ::: "memory");             \
    __builtin_amdgcn_s_barrier();                                           \
    MEMFENCE;                                                               \
    BISSUE((S) + 1);      /* junk at S=15 (wraps to kts 0,1) - never read */\
    MEMFENCE;                                                               \
    const unsigned char* ap_ = &ldsA[(S) & 1][0];                           \
    const unsigned char* bp_ = &ldsB[(S) & 1][cg * 4096 + lane * 16];       \
    __builtin_amdgcn_s_setprio(1);                                          \
    _Pragma("unroll")                                                       \
    for (int j = 0; j < 2; ++j) {                                           \
      f16x8 a0_ = *(const f16x8*)(ap_ + j * 4096 + aroff);                  \
      f16x8 a1_ = *(const f16x8*)(ap_ + j * 4096 + aroff + 512);            \
      const unsigned char* bb_ = bp_ + j * 8192;                            \
      _Pragma("unroll")                                                     \
      for (int t = 0; t < 4; ++t) {                                         \
        f16x8 bh_ = *(const f16x8*)(bb_ + t * 1024);                        \
        acc[0][t] = __builtin_amdgcn_mfma_f32_32x32x16_f16(a0_, bh_, acc[0][t], 0, 0, 0); \
        acc[1][t] = __builtin_amdgcn_mfma_f32_32x32x16_f16(a1_, bh_, acc[1][t], 0, 0, 0); \
      }                                                                     \
    }                                                                       \
    __builtin_amdgcn_s_setprio(0);                                          \
    MEMFENCE;                                                               \
    asm volatile("s_waitcnt vmcnt(4)" ::: "memory");  /* A(S+1) landed */   \
    AWRITE((S) + 1);                                                        \
    MEMFENCE;                                                               \
    AISSUE(((S) + 2) & 15);                                                 \
    MEMFENCE;                                                               \
  } while (0)

#pragma unroll 1
  for (int it = 0; it < 8; ++it) {
    BODY(it * 2);
    BODY(it * 2 + 1);
  }

  // epilogue: tanh + query-dot; 32-lane reduce; combine cg halves
  float sp[2][16];
#pragma unroll
  for (int f = 0; f < 2; ++f)
#pragma unroll
    for (int r = 0; r < 16; ++r) sp[f][r] = 0.f;
#pragma unroll
  for (int j = 0; j < 4; ++j) {
    const int col = ny * 256 + (cg * 4 + j) * 32 + l31;
    const float bb2 = bias[col];
    const float qq = query[col];
#pragma unroll
    for (int f = 0; f < 2; ++f)
#pragma unroll
      for (int r = 0; r < 16; ++r)
        sp[f][r] += fast_tanh(acc[f][j][r] + bb2) * qq;
  }
  __syncthreads();
#pragma unroll
  for (int f = 0; f < 2; ++f)
#pragma unroll
    for (int r = 0; r < 16; ++r) {
      float v = sp[f][r];
      v += __shfl_xor(v, 1);
      v += __shfl_xor(v, 2);
      v += __shfl_xor(v, 4);
      v += __shfl_xor(v, 8);
      v += __shfl_xor(v, 16);
      if (l31 == 0)  // C row = (r&3) + 8*(r>>2) + 4*kh  (m74/m101 layout)
        comb[cg][rg * 64 + f * 32 + (r & 3) + 8 * (r >> 2) + 4 * kh] = v;
    }
  __syncthreads();
  if (tid < 128)
    score_part[(size_t)ny * N + brow0 + tid] = comb[0][tid] + comb[1][tid];
}

// Per-graph: segmented softmax over (sp0+sp1) + weighted sum of x rows -> out[g][512]
__global__ __launch_bounds__(256) void k_softmax_out(
    const float* __restrict__ x, const void* __restrict__ segp,
    const float* __restrict__ sp0, const float* __restrict__ sp1,
    float* __restrict__ out, int N) {
  const int g = blockIdx.x;
  const int tid = threadIdx.x;

  // dtype probe: int64 element N/2-1 is a graph id (<NG) iff buffer is int64.
  const long long probe = ((const long long*)segp)[N / 2 - 1];
  const bool is64 = ((unsigned long long)probe < (unsigned long long)NG);
  const long long* s64 = (const long long*)segp;
  const int* s32 = (const int*)segp;

  int s0, s1;
  {
    int lo = 0, hi = N;
    while (lo < hi) {
      int m = (lo + hi) >> 1;
      long long v = is64 ? s64[m] : (long long)s32[m];
      if (v < (long long)g) lo = m + 1; else hi = m;
    }
    s0 = lo;
    lo = s0; hi = N;
    while (lo < hi) {
      int m = (lo + hi) >> 1;
      long long v = is64 ? s64[m] : (long long)s32[m];
      if (v < (long long)(g + 1)) lo = m + 1; else hi = m;
    }
    s1 = lo;
  }

  __shared__ float red[4];
  __shared__ float wbuf[512];

  float lm = -INFINITY;
  for (int i = s0 + tid; i < s1; i += 256) lm = fmaxf(lm, sp0[i] + sp1[i]);
#pragma unroll
  for (int m = 1; m < 64; m <<= 1) lm = fmaxf(lm, __shfl_xor(lm, m));
  if ((tid & 63) == 0) red[tid >> 6] = lm;
  __syncthreads();
  const float mx = fmaxf(fmaxf(red[0], red[1]), fmaxf(red[2], red[3]));
  __syncthreads();

  float ls = 0.f;
  for (int i = s0 + tid; i < s1; i += 256) ls += expf(sp0[i] + sp1[i] - mx);
#pragma unroll
  for (int m = 1; m < 64; m <<= 1) ls += __shfl_xor(ls, m);
  if ((tid & 63) == 0) red[tid >> 6] = ls;
  __syncthreads();
  const float sum = red[0] + red[1] + red[2] + red[3];
  const float inv = sum > 0.f ? 1.0f / sum : 0.f;

  float a0 = 0.f, a1 = 0.f;
  const int c = tid * 2;
  for (int base = s0; base < s1; base += 512) {
    const int cnt = min(512, s1 - base);
    __syncthreads();
    for (int i = tid; i < cnt; i += 256)
      wbuf[i] = expf(sp0[base + i] + sp1[base + i] - mx) * inv;
    __syncthreads();
#pragma unroll 4
    for (int j = 0; j < cnt; ++j) {
      const float w = wbuf[j];
      const float2 xv = *(const float2*)(x + (size_t)(base + j) * DD + c);
      a0 = fmaf(w, xv.x, a0);
      a1 = fmaf(w, xv.y, a1);
    }
  }
  float* op = out + (size_t)g * DD + c;
  op[0] = a0;
  op[1] = a1;
}

extern "C" void kernel_launch(void* const* d_in, const int* in_sizes, int n_in,
                              void* d_out, int out_size, void* d_ws, size_t ws_size,
                              hipStream_t stream) {
  const float* x = (const float*)d_in[0];
  const void* seg = d_in[1];
  const float* W = (const float*)d_in[2];
  const float* b = (const float*)d_in[3];
  const float* q = (const float*)d_in[4];
  float* out = (float*)d_out;
  const int N = in_sizes[0] / DD;  // 131072

  unsigned char* Whl = (unsigned char*)d_ws;                 // 512 KB packed W (f16)
  float* sp0 = (float*)(Whl + 524288);                       // N partial scores (ny=0)
  float* sp1 = sp0 + N;                                      // N partial scores (ny=1)

  k_convert_w<<<128, 256, 0, stream>>>(W, Whl);
  dim3 grid(2, N / 128);                                     // ny fastest -> x-row cache reuse
  k_gemm_score<<<grid, 256, 0, stream>>>(x, Whl, b, q, sp0, N);
  k_softmax_out<<<NG, 256, 0, stream>>>(x, seg, sp0, sp1, out, N);
}

// Round 20
// 171.264 us; speedup vs baseline: 1.5164x; 1.0216x over previous
//
#include <hip/hip_runtime.h>

typedef _Float16 f16x8 __attribute__((ext_vector_type(8)));
typedef _Float16 f16x4 __attribute__((ext_vector_type(4)));
typedef __fp16 fp16v2 __attribute__((ext_vector_type(2)));
typedef _Float16 f16v2 __attribute__((ext_vector_type(2)));
typedef short short8 __attribute__((ext_vector_type(8)));
typedef float f32x16 __attribute__((ext_vector_type(16)));

#define DD 512
#define NG 512

typedef __attribute__((address_space(3))) void lds_void;
typedef __attribute__((address_space(1))) void glb_void;

static __device__ __forceinline__ void gload_lds16(const void* g, void* l) {
  __builtin_amdgcn_global_load_lds((const glb_void*)g, (lds_void*)l, 16, 0, 0);
}

#define MEMFENCE asm volatile("" ::: "memory")

static __device__ __forceinline__ f16v2 pk16(float a, float b) {
  fp16v2 p = __builtin_amdgcn_cvt_pkrtz(a, b);
  return __builtin_bit_cast(f16v2, p);
}

// fast tanh via exp2: tanh(v) = 1 - 2/(exp2(v*2*log2e)+1)  (~1e-6 abs err)
static __device__ __forceinline__ float fast_tanh(float v) {
  float e = __builtin_amdgcn_exp2f(v * 2.8853900817779268f);
  return 1.0f - 2.0f * __builtin_amdgcn_rcpf(e + 1.0f);
}

// Whl layout (f16 RTE): [ny(2)][kt(32)][ct(8)][lane(64)=khalf*32+c31][8 f16]
// One (ny,kt) slice = 8 KB contiguous -> staged linearly by global_load_lds.
// B-fragment ds_read = lds + ct*1024 + lane*16: 64 lanes read 1024 contiguous
// bytes -> zero bank conflicts (verified rounds 4/9/11/17).
__global__ __launch_bounds__(256) void k_convert_w(const float* __restrict__ W,
                                                   unsigned char* __restrict__ Whl) {
  int t = blockIdx.x * 256 + threadIdx.x;   // 32768 = 512 W-rows x 64 kgroups(8)
  int r512 = t >> 6, kg = t & 63;
  int ny = r512 >> 8, col = r512 & 255;
  int ct = col >> 5, c31 = col & 31;
  int kt = kg >> 1, khalf = kg & 1;
  const float* p = W + (size_t)r512 * DD + kg * 8;
  short8 h;
#pragma unroll
  for (int j = 0; j < 8; ++j) {
    _Float16 hh = (_Float16)p[j];              // RTE
    h[j] = (short)__builtin_bit_cast(unsigned short, hh);
  }
  unsigned char* dst = Whl + (size_t)ny * 262144 + (size_t)kt * 8192 +
                       ct * 1024 + (khalf * 32 + c31) * 16;
  *(short8*)dst = h;
}

// Fused GEMM(tanh-gate)+query-dot.  R19 schedule (best measured), fully
// unrolled: 16 BODY(literal S) -> every staging/read offset folds to an
// immediate (cuts runtime addressing VALU).  FIFO invariant at body top:
// [B(S) x4 older, A(S+1) x4 newer] -> vmcnt(4) exact.
// Wave = 64 rows x 128 cols (acc[2][4] = 128 AGPR); block = 4 waves = 128
// rows x 256 cols (ny = col half); 2-kt bodies (16 barriers); ring-2
// double-buffer (B 16KB + A 8KB per buf); f16 A in conflict-free
// [kh-plane][row][16B] layout.  49 KB LDS -> 2 blocks/CU.
__global__ __launch_bounds__(256, 2) void k_gemm_score(
    const float* __restrict__ x, const unsigned char* __restrict__ Whl,
    const float* __restrict__ bias, const float* __restrict__ query,
    float* __restrict__ score_part, int N) {
  __shared__ unsigned char ldsB[2][16384];
  __shared__ unsigned char ldsA[2][8192];
  __shared__ float comb[2][128];
  const int tid = threadIdx.x;
  const int wave = tid >> 6;
  const int lane = tid & 63;
  const int l31 = lane & 31;
  const int kh = lane >> 5;          // k-half within fragment
  const int rg = wave >> 1;          // row-group: rows rg*64..rg*64+63
  const int cg = wave & 1;           // col-group: cts cg*4..cg*4+3
  const int ny = blockIdx.x;
  const int brow0 = blockIdx.y * 128;

  const unsigned char* wsrc = Whl + (size_t)ny * 262144 +
                              (size_t)wave * 2048 + (size_t)lane * 16;

  // A: thread covers chunks (row = tid>>2 and +64, kq = tid&3) of each
  // 128-row x 16-k slice.
  const float* asrc = x + (size_t)(brow0 + (tid >> 2)) * DD + (tid & 3) * 4;
  // f16 write: [kt-in-pair(4KB)][kh(2KB)][row(128)x16B], half = kq&1:
  const int awoff = ((tid & 3) >> 1) * 2048 + (tid >> 2) * 16 + (tid & 1) * 8;
  // f16 read: fragment row rg*64 + f*32 + l31, plane kh
  const int aroff = kh * 2048 + (rg * 64 + l31) * 16;

  f32x16 acc[2][4];
#pragma unroll
  for (int f = 0; f < 2; ++f)
#pragma unroll
    for (int j = 0; j < 4; ++j)
#pragma unroll
      for (int r = 0; r < 16; ++r) acc[f][j][r] = 0.f;

  float4 aB[4];   // [kt-in-pair][chunk c]

#define AISSUE(S)                                                           \
  do {                                                                      \
    _Pragma("unroll")                                                       \
    for (int j = 0; j < 2; ++j)                                             \
      _Pragma("unroll")                                                     \
      for (int c = 0; c < 2; ++c)                                           \
        aB[j * 2 + c] = *(const float4*)(asrc + (size_t)c * 64 * DD +       \
                                         ((2 * (S) + j) & 31) * 16);        \
  } while (0)

#define AWRITE(S)                                                           \
  do {                                                                      \
    unsigned char* base_ = &ldsA[(S) & 1][0];                               \
    _Pragma("unroll")                                                       \
    for (int j = 0; j < 2; ++j)                                             \
      _Pragma("unroll")                                                     \
      for (int c = 0; c < 2; ++c) {                                         \
        const float4 v_ = aB[j * 2 + c];                                    \
        f16v2 lo_ = pk16(v_.x, v_.y);                                       \
        f16v2 hi_ = pk16(v_.z, v_.w);                                       \
        f16x4 w_ = {lo_[0], lo_[1], hi_[0], hi_[1]};                        \
        *(f16x4*)(base_ + j * 4096 + awoff + c * 1024) = w_;                \
      }                                                                     \
  } while (0)

#define BISSUE(S)                                                           \
  do {                                                                      \
    unsigned char* db_ = &ldsB[(S) & 1][wave * 2048];                       \
    _Pragma("unroll")                                                       \
    for (int j = 0; j < 2; ++j) {                                           \
      const unsigned char* sb_ = wsrc + (size_t)((2 * (S) + j) & 31) * 8192;\
      gload_lds16(sb_, db_ + j * 8192);                                     \
      gload_lds16(sb_ + 1024, db_ + j * 8192 + 1024);                       \
    }                                                                       \
  } while (0)

  // prologue: regs<-A(0); drain; LDS<-A(0); B(0) staged (OLDER); regs<-A(1)
  // (NEWER) -> body-0 top sees FIFO [B(0)x4, A(1)x4].
  AISSUE(0);
  MEMFENCE;
  asm volatile("s_waitcnt vmcnt(0)" ::: "memory");
  AWRITE(0);
  MEMFENCE;
  BISSUE(0);
  MEMFENCE;
  AISSUE(1);
  MEMFENCE;

  // BODY(S): vmcnt(4) drains B(S) only; lgkm(0) drains prior A ds_writes;
  // barrier; BISSUE(S+1); MFMA on slice S; vmcnt(4) drains A(S+1) regs
  // (leaves B(S+1) in flight); AWRITE(S+1); AISSUE(S+2).
#define BODY(S)                                                             \
  do {                                                                      \
    asm volatile("s_waitcnt vmcnt(4) lgkmcnt(0)" ::: "memory");             \
    __builtin_amdgcn_s_barrier();                                           \
    MEMFENCE;                                                               \
    BISSUE((S) + 1);      /* junk at S=15 (wraps to kts 0,1) - never read */\
    MEMFENCE;                                                               \
    const unsigned char* ap_ = &ldsA[(S) & 1][0];                           \
    const unsigned char* bp_ = &ldsB[(S) & 1][cg * 4096 + lane * 16];       \
    __builtin_amdgcn_s_setprio(1);                                          \
    _Pragma("unroll")                                                       \
    for (int j = 0; j < 2; ++j) {                                           \
      f16x8 a0_ = *(const f16x8*)(ap_ + j * 4096 + aroff);                  \
      f16x8 a1_ = *(const f16x8*)(ap_ + j * 4096 + aroff + 512);            \
      const unsigned char* bb_ = bp_ + j * 8192;                            \
      _Pragma("unroll")                                                     \
      for (int t = 0; t < 4; ++t) {                                         \
        f16x8 bh_ = *(const f16x8*)(bb_ + t * 1024);                        \
        acc[0][t] = __builtin_amdgcn_mfma_f32_32x32x16_f16(a0_, bh_, acc[0][t], 0, 0, 0); \
        acc[1][t] = __builtin_amdgcn_mfma_f32_32x32x16_f16(a1_, bh_, acc[1][t], 0, 0, 0); \
      }                                                                     \
    }                                                                       \
    __builtin_amdgcn_s_setprio(0);                                          \
    MEMFENCE;                                                               \
    asm volatile("s_waitcnt vmcnt(4)" ::: "memory");  /* A(S+1) landed */   \
    AWRITE((S) + 1);                                                        \
    MEMFENCE;                                                               \
    AISSUE(((S) + 2) & 15);                                                 \
    MEMFENCE;                                                               \
  } while (0)

  // fully unrolled: literal S folds all ring/stage offsets to immediates
  BODY(0);  BODY(1);  BODY(2);  BODY(3);
  BODY(4);  BODY(5);  BODY(6);  BODY(7);
  BODY(8);  BODY(9);  BODY(10); BODY(11);
  BODY(12); BODY(13); BODY(14); BODY(15);

  // epilogue: tanh + query-dot; 32-lane reduce; combine cg halves
  float sp[2][16];
#pragma unroll
  for (int f = 0; f < 2; ++f)
#pragma unroll
    for (int r = 0; r < 16; ++r) sp[f][r] = 0.f;
#pragma unroll
  for (int j = 0; j < 4; ++j) {
    const int col = ny * 256 + (cg * 4 + j) * 32 + l31;
    const float bb2 = bias[col];
    const float qq = query[col];
#pragma unroll
    for (int f = 0; f < 2; ++f)
#pragma unroll
      for (int r = 0; r < 16; ++r)
        sp[f][r] += fast_tanh(acc[f][j][r] + bb2) * qq;
  }
  __syncthreads();
#pragma unroll
  for (int f = 0; f < 2; ++f)
#pragma unroll
    for (int r = 0; r < 16; ++r) {
      float v = sp[f][r];
      v += __shfl_xor(v, 1);
      v += __shfl_xor(v, 2);
      v += __shfl_xor(v, 4);
      v += __shfl_xor(v, 8);
      v += __shfl_xor(v, 16);
      if (l31 == 0)  // C row = (r&3) + 8*(r>>2) + 4*kh  (m74/m101 layout)
        comb[cg][rg * 64 + f * 32 + (r & 3) + 8 * (r >> 2) + 4 * kh] = v;
    }
  __syncthreads();
  if (tid < 128)
    score_part[(size_t)ny * N + brow0 + tid] = comb[0][tid] + comb[1][tid];
}

// Per-graph: segmented softmax over (sp0+sp1) + weighted sum of x rows -> out[g][512]
__global__ __launch_bounds__(256) void k_softmax_out(
    const float* __restrict__ x, const void* __restrict__ segp,
    const float* __restrict__ sp0, const float* __restrict__ sp1,
    float* __restrict__ out, int N) {
  const int g = blockIdx.x;
  const int tid = threadIdx.x;

  // dtype probe: int64 element N/2-1 is a graph id (<NG) iff buffer is int64.
  const long long probe = ((const long long*)segp)[N / 2 - 1];
  const bool is64 = ((unsigned long long)probe < (unsigned long long)NG);
  const long long* s64 = (const long long*)segp;
  const int* s32 = (const int*)segp;

  int s0, s1;
  {
    int lo = 0, hi = N;
    while (lo < hi) {
      int m = (lo + hi) >> 1;
      long long v = is64 ? s64[m] : (long long)s32[m];
      if (v < (long long)g) lo = m + 1; else hi = m;
    }
    s0 = lo;
    lo = s0; hi = N;
    while (lo < hi) {
      int m = (lo + hi) >> 1;
      long long v = is64 ? s64[m] : (long long)s32[m];
      if (v < (long long)(g + 1)) lo = m + 1; else hi = m;
    }
    s1 = lo;
  }

  __shared__ float red[4];
  __shared__ float wbuf[512];

  float lm = -INFINITY;
  for (int i = s0 + tid; i < s1; i += 256) lm = fmaxf(lm, sp0[i] + sp1[i]);
#pragma unroll
  for (int m = 1; m < 64; m <<= 1) lm = fmaxf(lm, __shfl_xor(lm, m));
  if ((tid & 63) == 0) red[tid >> 6] = lm;
  __syncthreads();
  const float mx = fmaxf(fmaxf(red[0], red[1]), fmaxf(red[2], red[3]));
  __syncthreads();

  float ls = 0.f;
  for (int i = s0 + tid; i < s1; i += 256) ls += expf(sp0[i] + sp1[i] - mx);
#pragma unroll
  for (int m = 1; m < 64; m <<= 1) ls += __shfl_xor(ls, m);
  if ((tid & 63) == 0) red[tid >> 6] = ls;
  __syncthreads();
  const float sum = red[0] + red[1] + red[2] + red[3];
  const float inv = sum > 0.f ? 1.0f / sum : 0.f;

  float a0 = 0.f, a1 = 0.f;
  const int c = tid * 2;
  for (int base = s0; base < s1; base += 512) {
    const int cnt = min(512, s1 - base);
    __syncthreads();
    for (int i = tid; i < cnt; i += 256)
      wbuf[i] = expf(sp0[base + i] + sp1[base + i] - mx) * inv;
    __syncthreads();
#pragma unroll 8
    for (int j = 0; j < cnt; ++j) {
      const float w = wbuf[j];
      const float2 xv = *(const float2*)(x + (size_t)(base + j) * DD + c);
      a0 = fmaf(w, xv.x, a0);
      a1 = fmaf(w, xv.y, a1);
    }
  }
  float* op = out + (size_t)g * DD + c;
  op[0] = a0;
  op[1] = a1;
}

extern "C" void kernel_launch(void* const* d_in, const int* in_sizes, int n_in,
                              void* d_out, int out_size, void* d_ws, size_t ws_size,
                              hipStream_t stream) {
  const float* x = (const float*)d_in[0];
  const void* seg = d_in[1];
  const float* W = (const float*)d_in[2];
  const float* b = (const float*)d_in[3];
  const float* q = (const float*)d_in[4];
  float* out = (float*)d_out;
  const int N = in_sizes[0] / DD;  // 131072

  unsigned char* Whl = (unsigned char*)d_ws;                 // 512 KB packed W (f16)
  float* sp0 = (float*)(Whl + 524288);                       // N partial scores (ny=0)
  float* sp1 = sp0 + N;                                      // N partial scores (ny=1)

  k_convert_w<<<128, 256, 0, stream>>>(W, Whl);
  dim3 grid(2, N / 128);                                     // ny fastest -> x-row cache reuse
  k_gemm_score<<<grid, 256, 0, stream>>>(x, Whl, b, q, sp0, N);
  k_softmax_out<<<NG, 256, 0, stream>>>(x, seg, sp0, sp1, out, N);
}

// Round 21
// 162.439 us; speedup vs baseline: 1.5988x; 1.0543x over previous
//
#include <hip/hip_runtime.h>

typedef _Float16 f16x8 __attribute__((ext_vector_type(8)));
typedef _Float16 f16x4 __attribute__((ext_vector_type(4)));
typedef __fp16 fp16v2 __attribute__((ext_vector_type(2)));
typedef _Float16 f16v2 __attribute__((ext_vector_type(2)));
typedef short short8 __attribute__((ext_vector_type(8)));
typedef float f32x16 __attribute__((ext_vector_type(16)));

#define DD 512
#define NG 512

#define MEMFENCE asm volatile("" ::: "memory")

static __device__ __forceinline__ f16v2 pk16(float a, float b) {
  fp16v2 p = __builtin_amdgcn_cvt_pkrtz(a, b);
  return __builtin_bit_cast(f16v2, p);
}

// fast tanh via exp2: tanh(v) = 1 - 2/(exp2(v*2*log2e)+1)  (~1e-6 abs err)
static __device__ __forceinline__ float fast_tanh(float v) {
  float e = __builtin_amdgcn_exp2f(v * 2.8853900817779268f);
  return 1.0f - 2.0f * __builtin_amdgcn_rcpf(e + 1.0f);
}

// Whl layout (f16 RTE): [ny(2)][kt(32)][ct(8)][lane(64)=khalf*32+c31][8 f16]
// B-fragment = 1 KB contiguous at kt*8192 + ct*1024 + lane*16 -> a direct
// global_load_dwordx4 per fragment is perfectly coalesced.  Whl = 512 KB,
// read by all blocks -> L2-resident.
__global__ __launch_bounds__(256) void k_convert_w(const float* __restrict__ W,
                                                   unsigned char* __restrict__ Whl) {
  int t = blockIdx.x * 256 + threadIdx.x;   // 32768 = 512 W-rows x 64 kgroups(8)
  int r512 = t >> 6, kg = t & 63;
  int ny = r512 >> 8, col = r512 & 255;
  int ct = col >> 5, c31 = col & 31;
  int kt = kg >> 1, khalf = kg & 1;
  const float* p = W + (size_t)r512 * DD + kg * 8;
  short8 h;
#pragma unroll
  for (int j = 0; j < 8; ++j) {
    _Float16 hh = (_Float16)p[j];              // RTE
    h[j] = (short)__builtin_bit_cast(unsigned short, hh);
  }
  unsigned char* dst = Whl + (size_t)ny * 262144 + (size_t)kt * 8192 +
                       ct * 1024 + (khalf * 32 + c31) * 16;
  *(short8*)dst = h;
}

// Fused GEMM(tanh-gate)+query-dot.  R19/20 schedule with B moved OUT of LDS:
// B fragments load straight from L2-resident Whl into VGPRs (coalesced
// dwordx4), single-kt double set (b0/b1, 32 VGPR) so arch+acc stays <= 256
// (2 waves/SIMD).  LDS keeps only the A path (f16, conflict-free
// [kh-plane][row][16B], ring-2).  Per body: 1 barrier + 1 lgkm0; ALL global
// waits are compiler reg-dependency counted (no vmcnt asm).
// Wave = 64 rows x 128 cols (acc[2][4] = 128 AGPR); block = 4 waves = 128
// rows x 256 cols (ny = col half); 2-kt bodies, fully unrolled.  17.4 KB LDS.
__global__ __launch_bounds__(256, 2) void k_gemm_score(
    const float* __restrict__ x, const unsigned char* __restrict__ Whl,
    const float* __restrict__ bias, const float* __restrict__ query,
    float* __restrict__ score_part, int N) {
  __shared__ unsigned char ldsA[2][8192];
  __shared__ float comb[2][128];
  const int tid = threadIdx.x;
  const int wave = tid >> 6;
  const int lane = tid & 63;
  const int l31 = lane & 31;
  const int kh = lane >> 5;          // k-half within fragment
  const int rg = wave >> 1;          // row-group: rows rg*64..rg*64+63
  const int cg = wave & 1;           // col-group: cts cg*4..cg*4+3
  const int ny = blockIdx.x;
  const int brow0 = blockIdx.y * 128;

  // B direct-load base: fragment (kt, ct=cg*4+t) at + kt*8192 + t*1024
  const unsigned char* bsrc = Whl + (size_t)ny * 262144 + cg * 4096 +
                              (size_t)lane * 16;

  // A: thread covers chunks (row = tid>>2 and +64, kq = tid&3) of each
  // 128-row x 16-k slice.
  const float* asrc = x + (size_t)(brow0 + (tid >> 2)) * DD + (tid & 3) * 4;
  // f16 write: [kt-in-pair(4KB)][kh(2KB)][row(128)x16B], half = kq&1:
  const int awoff = ((tid & 3) >> 1) * 2048 + (tid >> 2) * 16 + (tid & 1) * 8;
  // f16 read: fragment row rg*64 + f*32 + l31, plane kh
  const int aroff = kh * 2048 + (rg * 64 + l31) * 16;

  f32x16 acc[2][4];
#pragma unroll
  for (int f = 0; f < 2; ++f)
#pragma unroll
    for (int j = 0; j < 4; ++j)
#pragma unroll
      for (int r = 0; r < 16; ++r) acc[f][j][r] = 0.f;

  float4 aB[4];        // A reg staging [kt-in-pair][chunk c]
  f16x8 b0[4], b1[4];  // B fragment sets (single kt each)

#define AISSUE(S)                                                           \
  do {                                                                      \
    _Pragma("unroll")                                                       \
    for (int j = 0; j < 2; ++j)                                             \
      _Pragma("unroll")                                                     \
      for (int c = 0; c < 2; ++c)                                           \
        aB[j * 2 + c] = *(const float4*)(asrc + (size_t)c * 64 * DD +       \
                                         ((2 * (S) + j) & 31) * 16);        \
  } while (0)

#define AWRITE(S)                                                           \
  do {                                                                      \
    unsigned char* base_ = &ldsA[(S) & 1][0];                               \
    _Pragma("unroll")                                                       \
    for (int j = 0; j < 2; ++j)                                             \
      _Pragma("unroll")                                                     \
      for (int c = 0; c < 2; ++c) {                                         \
        const float4 v_ = aB[j * 2 + c];                                    \
        f16v2 lo_ = pk16(v_.x, v_.y);                                       \
        f16v2 hi_ = pk16(v_.z, v_.w);                                       \
        f16x4 w_ = {lo_[0], lo_[1], hi_[0], hi_[1]};                        \
        *(f16x4*)(base_ + j * 4096 + awoff + c * 1024) = w_;                \
      }                                                                     \
  } while (0)

#define BLOAD(KT, R)                                                        \
  do {                                                                      \
    const unsigned char* sb_ = bsrc + (size_t)((KT) & 31) * 8192;           \
    _Pragma("unroll")                                                       \
    for (int t = 0; t < 4; ++t)                                             \
      R[t] = *(const f16x8*)(sb_ + t * 1024);                               \
  } while (0)

#define MFMA_HALF(AP, J2, B)                                                \
  do {                                                                      \
    f16x8 a0_ = *(const f16x8*)((AP) + (J2) * 4096 + aroff);                \
    f16x8 a1_ = *(const f16x8*)((AP) + (J2) * 4096 + aroff + 512);          \
    _Pragma("unroll")                                                       \
    for (int t = 0; t < 4; ++t) {                                           \
      acc[0][t] = __builtin_amdgcn_mfma_f32_32x32x16_f16(a0_, B[t], acc[0][t], 0, 0, 0); \
      acc[1][t] = __builtin_amdgcn_mfma_f32_32x32x16_f16(a1_, B[t], acc[1][t], 0, 0, 0); \
    }                                                                       \
  } while (0)

  // prologue: A(0) regs -> LDS; b0 <- kt 0; A(1) regs in flight.
  AISSUE(0);
  MEMFENCE;
  AWRITE(0);          // compiler inserts the vmcnt wait for aB
  MEMFENCE;
  BLOAD(0, b0);
  MEMFENCE;
  AISSUE(1);
  MEMFENCE;

  // BODY(S): lgkm0+barrier (A slice S visible) -> b1 <- kt 2S+1 ->
  // MFMA half0 (b0, A j2=0) -> b0 <- kt 2S+2 -> MFMA half1 (b1, A j2=1) ->
  // AWRITE(S+1) -> AISSUE(S+2).  All global waits compiler-counted.
#define BODY(S)                                                             \
  do {                                                                      \
    asm volatile("s_waitcnt lgkmcnt(0)" ::: "memory");                      \
    __builtin_amdgcn_s_barrier();                                           \
    MEMFENCE;                                                               \
    BLOAD(2 * (S) + 1, b1);                                                 \
    MEMFENCE;                                                               \
    const unsigned char* ap_ = &ldsA[(S) & 1][0];                           \
    __builtin_amdgcn_s_setprio(1);                                          \
    MFMA_HALF(ap_, 0, b0);                                                  \
    __builtin_amdgcn_s_setprio(0);                                          \
    MEMFENCE;                                                               \
    BLOAD(2 * (S) + 2, b0);                                                 \
    MEMFENCE;                                                               \
    __builtin_amdgcn_s_setprio(1);                                          \
    MFMA_HALF(ap_, 1, b1);                                                  \
    __builtin_amdgcn_s_setprio(0);                                          \
    MEMFENCE;                                                               \
    AWRITE((S) + 1);                                                        \
    MEMFENCE;                                                               \
    AISSUE(((S) + 2) & 15);                                                 \
    MEMFENCE;                                                               \
  } while (0)

  // fully unrolled: literal S folds all offsets to immediates
  BODY(0);  BODY(1);  BODY(2);  BODY(3);
  BODY(4);  BODY(5);  BODY(6);  BODY(7);
  BODY(8);  BODY(9);  BODY(10); BODY(11);
  BODY(12); BODY(13); BODY(14); BODY(15);

  // epilogue: tanh + query-dot; 32-lane reduce; combine cg halves
  float sp[2][16];
#pragma unroll
  for (int f = 0; f < 2; ++f)
#pragma unroll
    for (int r = 0; r < 16; ++r) sp[f][r] = 0.f;
#pragma unroll
  for (int j = 0; j < 4; ++j) {
    const int col = ny * 256 + (cg * 4 + j) * 32 + l31;
    const float bb2 = bias[col];
    const float qq = query[col];
#pragma unroll
    for (int f = 0; f < 2; ++f)
#pragma unroll
      for (int r = 0; r < 16; ++r)
        sp[f][r] += fast_tanh(acc[f][j][r] + bb2) * qq;
  }
  __syncthreads();
#pragma unroll
  for (int f = 0; f < 2; ++f)
#pragma unroll
    for (int r = 0; r < 16; ++r) {
      float v = sp[f][r];
      v += __shfl_xor(v, 1);
      v += __shfl_xor(v, 2);
      v += __shfl_xor(v, 4);
      v += __shfl_xor(v, 8);
      v += __shfl_xor(v, 16);
      if (l31 == 0)  // C row = (r&3) + 8*(r>>2) + 4*kh  (m74/m101 layout)
        comb[cg][rg * 64 + f * 32 + (r & 3) + 8 * (r >> 2) + 4 * kh] = v;
    }
  __syncthreads();
  if (tid < 128)
    score_part[(size_t)ny * N + brow0 + tid] = comb[0][tid] + comb[1][tid];
}

// Per-graph: segmented softmax over (sp0+sp1) + weighted sum of x rows -> out[g][512]
__global__ __launch_bounds__(256) void k_softmax_out(
    const float* __restrict__ x, const void* __restrict__ segp,
    const float* __restrict__ sp0, const float* __restrict__ sp1,
    float* __restrict__ out, int N) {
  const int g = blockIdx.x;
  const int tid = threadIdx.x;

  // dtype probe: int64 element N/2-1 is a graph id (<NG) iff buffer is int64.
  const long long probe = ((const long long*)segp)[N / 2 - 1];
  const bool is64 = ((unsigned long long)probe < (unsigned long long)NG);
  const long long* s64 = (const long long*)segp;
  const int* s32 = (const int*)segp;

  int s0, s1;
  {
    int lo = 0, hi = N;
    while (lo < hi) {
      int m = (lo + hi) >> 1;
      long long v = is64 ? s64[m] : (long long)s32[m];
      if (v < (long long)g) lo = m + 1; else hi = m;
    }
    s0 = lo;
    lo = s0; hi = N;
    while (lo < hi) {
      int m = (lo + hi) >> 1;
      long long v = is64 ? s64[m] : (long long)s32[m];
      if (v < (long long)(g + 1)) lo = m + 1; else hi = m;
    }
    s1 = lo;
  }

  __shared__ float red[4];
  __shared__ float wbuf[512];

  float lm = -INFINITY;
  for (int i = s0 + tid; i < s1; i += 256) lm = fmaxf(lm, sp0[i] + sp1[i]);
#pragma unroll
  for (int m = 1; m < 64; m <<= 1) lm = fmaxf(lm, __shfl_xor(lm, m));
  if ((tid & 63) == 0) red[tid >> 6] = lm;
  __syncthreads();
  const float mx = fmaxf(fmaxf(red[0], red[1]), fmaxf(red[2], red[3]));
  __syncthreads();

  float ls = 0.f;
  for (int i = s0 + tid; i < s1; i += 256) ls += expf(sp0[i] + sp1[i] - mx);
#pragma unroll
  for (int m = 1; m < 64; m <<= 1) ls += __shfl_xor(ls, m);
  if ((tid & 63) == 0) red[tid >> 6] = ls;
  __syncthreads();
  const float sum = red[0] + red[1] + red[2] + red[3];
  const float inv = sum > 0.f ? 1.0f / sum : 0.f;

  float a0 = 0.f, a1 = 0.f;
  const int c = tid * 2;
  for (int base = s0; base < s1; base += 512) {
    const int cnt = min(512, s1 - base);
    __syncthreads();
    for (int i = tid; i < cnt; i += 256)
      wbuf[i] = expf(sp0[base + i] + sp1[base + i] - mx) * inv;
    __syncthreads();
#pragma unroll 8
    for (int j = 0; j < cnt; ++j) {
      const float w = wbuf[j];
      const float2 xv = *(const float2*)(x + (size_t)(base + j) * DD + c);
      a0 = fmaf(w, xv.x, a0);
      a1 = fmaf(w, xv.y, a1);
    }
  }
  float* op = out + (size_t)g * DD + c;
  op[0] = a0;
  op[1] = a1;
}

extern "C" void kernel_launch(void* const* d_in, const int* in_sizes, int n_in,
                              void* d_out, int out_size, void* d_ws, size_t ws_size,
                              hipStream_t stream) {
  const float* x = (const float*)d_in[0];
  const void* seg = d_in[1];
  const float* W = (const float*)d_in[2];
  const float* b = (const float*)d_in[3];
  const float* q = (const float*)d_in[4];
  float* out = (float*)d_out;
  const int N = in_sizes[0] / DD;  // 131072

  unsigned char* Whl = (unsigned char*)d_ws;                 // 512 KB packed W (f16)
  float* sp0 = (float*)(Whl + 524288);                       // N partial scores (ny=0)
  float* sp1 = sp0 + N;                                      // N partial scores (ny=1)

  k_convert_w<<<128, 256, 0, stream>>>(W, Whl);
  dim3 grid(2, N / 128);                                     // ny fastest -> x-row cache reuse
  k_gemm_score<<<grid, 256, 0, stream>>>(x, Whl, b, q, sp0, N);
  k_softmax_out<<<NG, 256, 0, stream>>>(x, seg, sp0, sp1, out, N);
}

// Round 22
// 160.539 us; speedup vs baseline: 1.6177x; 1.0118x over previous
//
#include <hip/hip_runtime.h>

typedef _Float16 f16x8 __attribute__((ext_vector_type(8)));
typedef _Float16 f16x4 __attribute__((ext_vector_type(4)));
typedef __fp16 fp16v2 __attribute__((ext_vector_type(2)));
typedef _Float16 f16v2 __attribute__((ext_vector_type(2)));
typedef short short8 __attribute__((ext_vector_type(8)));
typedef float f32x16 __attribute__((ext_vector_type(16)));

#define DD 512
#define NG 512

#define MEMFENCE asm volatile("" ::: "memory")

static __device__ __forceinline__ f16v2 pk16(float a, float b) {
  fp16v2 p = __builtin_amdgcn_cvt_pkrtz(a, b);
  return __builtin_bit_cast(f16v2, p);
}

// fast tanh via exp2: tanh(v) = 1 - 2/(exp2(v*2*log2e)+1)  (~1e-6 abs err)
static __device__ __forceinline__ float fast_tanh(float v) {
  float e = __builtin_amdgcn_exp2f(v * 2.8853900817779268f);
  return 1.0f - 2.0f * __builtin_amdgcn_rcpf(e + 1.0f);
}

// Whl layout (f16 RTE): [ny(2)][kt(32)][ct(8)][lane(64)=khalf*32+c31][8 f16]
// B-fragment = 1 KB contiguous at kt*8192 + ct*1024 + lane*16 -> a direct
// global_load_dwordx4 per fragment is perfectly coalesced.  Whl = 512 KB,
// read by all blocks -> L2-resident.
__global__ __launch_bounds__(256) void k_convert_w(const float* __restrict__ W,
                                                   unsigned char* __restrict__ Whl) {
  int t = blockIdx.x * 256 + threadIdx.x;   // 32768 = 512 W-rows x 64 kgroups(8)
  int r512 = t >> 6, kg = t & 63;
  int ny = r512 >> 8, col = r512 & 255;
  int ct = col >> 5, c31 = col & 31;
  int kt = kg >> 1, khalf = kg & 1;
  const float* p = W + (size_t)r512 * DD + kg * 8;
  short8 h;
#pragma unroll
  for (int j = 0; j < 8; ++j) {
    _Float16 hh = (_Float16)p[j];              // RTE
    h[j] = (short)__builtin_bit_cast(unsigned short, hh);
  }
  unsigned char* dst = Whl + (size_t)ny * 262144 + (size_t)kt * 8192 +
                       ct * 1024 + (khalf * 32 + c31) * 16;
  *(short8*)dst = h;
}

// Fused GEMM(tanh-gate)+query-dot.  R21 dataflow (best measured), with
// intra-body fences REMOVED so the compiler interleaves B L2-loads / A
// ds-ops / MFMAs freely (counted waits auto-inserted), and the body tail
// reordered: BLOAD(b0') -> AWRITE -> AISSUE -> MFMA_HALF1 (AWRITE covers
// b1's L2 latency; body ends on MFMAs).  Per body: 1 barrier + 1 lgkm0.
// B: straight from L2-resident Whl to VGPRs (b0/b1 single-kt sets, 32 reg).
// A: f16 in LDS, conflict-free [kh-plane][row][16B], ring-2 (17.4 KB total).
// Wave = 64 rows x 128 cols (acc[2][4] = 128 AGPR); block = 4 waves = 128
// rows x 256 cols (ny = col half); 2-kt bodies, fully unrolled.
__global__ __launch_bounds__(256, 2) void k_gemm_score(
    const float* __restrict__ x, const unsigned char* __restrict__ Whl,
    const float* __restrict__ bias, const float* __restrict__ query,
    float* __restrict__ score_part, int N) {
  __shared__ unsigned char ldsA[2][8192];
  __shared__ float comb[2][128];
  const int tid = threadIdx.x;
  const int wave = tid >> 6;
  const int lane = tid & 63;
  const int l31 = lane & 31;
  const int kh = lane >> 5;          // k-half within fragment
  const int rg = wave >> 1;          // row-group: rows rg*64..rg*64+63
  const int cg = wave & 1;           // col-group: cts cg*4..cg*4+3
  const int ny = blockIdx.x;
  const int brow0 = blockIdx.y * 128;

  // B direct-load base: fragment (kt, ct=cg*4+t) at + kt*8192 + t*1024
  const unsigned char* bsrc = Whl + (size_t)ny * 262144 + cg * 4096 +
                              (size_t)lane * 16;

  // A: thread covers chunks (row = tid>>2 and +64, kq = tid&3) of each
  // 128-row x 16-k slice.
  const float* asrc = x + (size_t)(brow0 + (tid >> 2)) * DD + (tid & 3) * 4;
  // f16 write: [kt-in-pair(4KB)][kh(2KB)][row(128)x16B], half = kq&1:
  const int awoff = ((tid & 3) >> 1) * 2048 + (tid >> 2) * 16 + (tid & 1) * 8;
  // f16 read: fragment row rg*64 + f*32 + l31, plane kh
  const int aroff = kh * 2048 + (rg * 64 + l31) * 16;

  f32x16 acc[2][4];
#pragma unroll
  for (int f = 0; f < 2; ++f)
#pragma unroll
    for (int j = 0; j < 4; ++j)
#pragma unroll
      for (int r = 0; r < 16; ++r) acc[f][j][r] = 0.f;

  float4 aB[4];        // A reg staging [kt-in-pair][chunk c]
  f16x8 b0[4], b1[4];  // B fragment sets (single kt each)

#define AISSUE(S)                                                           \
  do {                                                                      \
    _Pragma("unroll")                                                       \
    for (int j = 0; j < 2; ++j)                                             \
      _Pragma("unroll")                                                     \
      for (int c = 0; c < 2; ++c)                                           \
        aB[j * 2 + c] = *(const float4*)(asrc + (size_t)c * 64 * DD +       \
                                         ((2 * (S) + j) & 31) * 16);        \
  } while (0)

#define AWRITE(S)                                                           \
  do {                                                                      \
    unsigned char* base_ = &ldsA[(S) & 1][0];                               \
    _Pragma("unroll")                                                       \
    for (int j = 0; j < 2; ++j)                                             \
      _Pragma("unroll")                                                     \
      for (int c = 0; c < 2; ++c) {                                         \
        const float4 v_ = aB[j * 2 + c];                                    \
        f16v2 lo_ = pk16(v_.x, v_.y);                                       \
        f16v2 hi_ = pk16(v_.z, v_.w);                                       \
        f16x4 w_ = {lo_[0], lo_[1], hi_[0], hi_[1]};                        \
        *(f16x4*)(base_ + j * 4096 + awoff + c * 1024) = w_;                \
      }                                                                     \
  } while (0)

#define BLOAD(KT, R)                                                        \
  do {                                                                      \
    const unsigned char* sb_ = bsrc + (size_t)((KT) & 31) * 8192;           \
    _Pragma("unroll")                                                       \
    for (int t = 0; t < 4; ++t)                                             \
      R[t] = *(const f16x8*)(sb_ + t * 1024);                               \
  } while (0)

#define MFMA_HALF(AP, J2, B)                                                \
  do {                                                                      \
    f16x8 a0_ = *(const f16x8*)((AP) + (J2) * 4096 + aroff);                \
    f16x8 a1_ = *(const f16x8*)((AP) + (J2) * 4096 + aroff + 512);          \
    _Pragma("unroll")                                                       \
    for (int t = 0; t < 4; ++t) {                                           \
      acc[0][t] = __builtin_amdgcn_mfma_f32_32x32x16_f16(a0_, B[t], acc[0][t], 0, 0, 0); \
      acc[1][t] = __builtin_amdgcn_mfma_f32_32x32x16_f16(a1_, B[t], acc[1][t], 0, 0, 0); \
    }                                                                       \
  } while (0)

  // prologue: A(0) regs -> LDS; b0 <- kt 0; A(1) regs in flight.
  AISSUE(0);
  MEMFENCE;
  AWRITE(0);          // compiler inserts the vmcnt wait for aB
  MEMFENCE;
  BLOAD(0, b0);
  MEMFENCE;
  AISSUE(1);
  MEMFENCE;

  // BODY(S): lgkm0+barrier (A slice S visible block-wide) -> then a single
  // compiler-scheduled region: BLOAD(b1) | MFMA half0 (b0) | BLOAD(b0') |
  // AWRITE(S+1) | AISSUE(S+2) | MFMA half1 (b1).  Slot audit: AWRITE targets
  // slot (S+1)&1, MFMA reads slot S&1 - disjoint, intra-body reorder safe.
#define BODY(S)                                                             \
  do {                                                                      \
    asm volatile("s_waitcnt lgkmcnt(0)" ::: "memory");                      \
    __builtin_amdgcn_s_barrier();                                           \
    MEMFENCE;                                                               \
    BLOAD(2 * (S) + 1, b1);                                                 \
    const unsigned char* ap_ = &ldsA[(S) & 1][0];                           \
    __builtin_amdgcn_s_setprio(1);                                          \
    MFMA_HALF(ap_, 0, b0);                                                  \
    __builtin_amdgcn_s_setprio(0);                                          \
    BLOAD(2 * (S) + 2, b0);                                                 \
    AWRITE((S) + 1);                                                        \
    AISSUE(((S) + 2) & 15);                                                 \
    __builtin_amdgcn_s_setprio(1);                                          \
    MFMA_HALF(ap_, 1, b1);                                                  \
    __builtin_amdgcn_s_setprio(0);                                          \
  } while (0)

  // fully unrolled: literal S folds all offsets to immediates
  BODY(0);  BODY(1);  BODY(2);  BODY(3);
  BODY(4);  BODY(5);  BODY(6);  BODY(7);
  BODY(8);  BODY(9);  BODY(10); BODY(11);
  BODY(12); BODY(13); BODY(14); BODY(15);

  // epilogue: tanh + query-dot; 32-lane reduce; combine cg halves
  float sp[2][16];
#pragma unroll
  for (int f = 0; f < 2; ++f)
#pragma unroll
    for (int r = 0; r < 16; ++r) sp[f][r] = 0.f;
#pragma unroll
  for (int j = 0; j < 4; ++j) {
    const int col = ny * 256 + (cg * 4 + j) * 32 + l31;
    const float bb2 = bias[col];
    const float qq = query[col];
#pragma unroll
    for (int f = 0; f < 2; ++f)
#pragma unroll
      for (int r = 0; r < 16; ++r)
        sp[f][r] += fast_tanh(acc[f][j][r] + bb2) * qq;
  }
  __syncthreads();
#pragma unroll
  for (int f = 0; f < 2; ++f)
#pragma unroll
    for (int r = 0; r < 16; ++r) {
      float v = sp[f][r];
      v += __shfl_xor(v, 1);
      v += __shfl_xor(v, 2);
      v += __shfl_xor(v, 4);
      v += __shfl_xor(v, 8);
      v += __shfl_xor(v, 16);
      if (l31 == 0)  // C row = (r&3) + 8*(r>>2) + 4*kh  (m74/m101 layout)
        comb[cg][rg * 64 + f * 32 + (r & 3) + 8 * (r >> 2) + 4 * kh] = v;
    }
  __syncthreads();
  if (tid < 128)
    score_part[(size_t)ny * N + brow0 + tid] = comb[0][tid] + comb[1][tid];
}

// Per-graph: segmented softmax over (sp0+sp1) + weighted sum of x rows -> out[g][512]
__global__ __launch_bounds__(256) void k_softmax_out(
    const float* __restrict__ x, const void* __restrict__ segp,
    const float* __restrict__ sp0, const float* __restrict__ sp1,
    float* __restrict__ out, int N) {
  const int g = blockIdx.x;
  const int tid = threadIdx.x;

  // dtype probe: int64 element N/2-1 is a graph id (<NG) iff buffer is int64.
  const long long probe = ((const long long*)segp)[N / 2 - 1];
  const bool is64 = ((unsigned long long)probe < (unsigned long long)NG);
  const long long* s64 = (const long long*)segp;
  const int* s32 = (const int*)segp;

  int s0, s1;
  {
    int lo = 0, hi = N;
    while (lo < hi) {
      int m = (lo + hi) >> 1;
      long long v = is64 ? s64[m] : (long long)s32[m];
      if (v < (long long)g) lo = m + 1; else hi = m;
    }
    s0 = lo;
    lo = s0; hi = N;
    while (lo < hi) {
      int m = (lo + hi) >> 1;
      long long v = is64 ? s64[m] : (long long)s32[m];
      if (v < (long long)(g + 1)) lo = m + 1; else hi = m;
    }
    s1 = lo;
  }

  __shared__ float red[4];
  __shared__ float wbuf[512];

  float lm = -INFINITY;
  for (int i = s0 + tid; i < s1; i += 256) lm = fmaxf(lm, sp0[i] + sp1[i]);
#pragma unroll
  for (int m = 1; m < 64; m <<= 1) lm = fmaxf(lm, __shfl_xor(lm, m));
  if ((tid & 63) == 0) red[tid >> 6] = lm;
  __syncthreads();
  const float mx = fmaxf(fmaxf(red[0], red[1]), fmaxf(red[2], red[3]));
  __syncthreads();

  float ls = 0.f;
  for (int i = s0 + tid; i < s1; i += 256) ls += expf(sp0[i] + sp1[i] - mx);
#pragma unroll
  for (int m = 1; m < 64; m <<= 1) ls += __shfl_xor(ls, m);
  if ((tid & 63) == 0) red[tid >> 6] = ls;
  __syncthreads();
  const float sum = red[0] + red[1] + red[2] + red[3];
  const float inv = sum > 0.f ? 1.0f / sum : 0.f;

  float a0 = 0.f, a1 = 0.f;
  const int c = tid * 2;
  for (int base = s0; base < s1; base += 512) {
    const int cnt = min(512, s1 - base);
    __syncthreads();
    for (int i = tid; i < cnt; i += 256)
      wbuf[i] = expf(sp0[base + i] + sp1[base + i] - mx) * inv;
    __syncthreads();
#pragma unroll 8
    for (int j = 0; j < cnt; ++j) {
      const float w = wbuf[j];
      const float2 xv = *(const float2*)(x + (size_t)(base + j) * DD + c);
      a0 = fmaf(w, xv.x, a0);
      a1 = fmaf(w, xv.y, a1);
    }
  }
  float* op = out + (size_t)g * DD + c;
  op[0] = a0;
  op[1] = a1;
}

extern "C" void kernel_launch(void* const* d_in, const int* in_sizes, int n_in,
                              void* d_out, int out_size, void* d_ws, size_t ws_size,
                              hipStream_t stream) {
  const float* x = (const float*)d_in[0];
  const void* seg = d_in[1];
  const float* W = (const float*)d_in[2];
  const float* b = (const float*)d_in[3];
  const float* q = (const float*)d_in[4];
  float* out = (float*)d_out;
  const int N = in_sizes[0] / DD;  // 131072

  unsigned char* Whl = (unsigned char*)d_ws;                 // 512 KB packed W (f16)
  float* sp0 = (float*)(Whl + 524288);                       // N partial scores (ny=0)
  float* sp1 = sp0 + N;                                      // N partial scores (ny=1)

  k_convert_w<<<128, 256, 0, stream>>>(W, Whl);
  dim3 grid(2, N / 128);                                     // ny fastest -> x-row cache reuse
  k_gemm_score<<<grid, 256, 0, stream>>>(x, Whl, b, q, sp0, N);
  k_softmax_out<<<NG, 256, 0, stream>>>(x, seg, sp0, sp1, out, N);
}